// Round 18
// baseline (161.708 us; speedup 1.0000x reference)
//
#include <hip/hip_runtime.h>
#include <math.h>

typedef __attribute__((ext_vector_type(8))) short bf16x8;   // 8 bf16 = 4 VGPR
typedef __attribute__((ext_vector_type(4))) float f32x4;    // MFMA acc
struct __align__(8)  us4 { unsigned short x,y,z,w; };
struct __align__(16) ui4 { unsigned x,y,z,w; };

#define SLOPE 0.2291666666666667f
constexpr int N0=4110, N1=4108, N2=4104, NX=4111;

__device__ __forceinline__ unsigned short f2bf(float f){
  unsigned u = __float_as_uint(f);
  u = (u + 0x7FFF + ((u>>16)&1)) >> 16;   // RNE
  return (unsigned short)u;
}
__device__ __forceinline__ float bf2f(unsigned short h){
  return __uint_as_float(((unsigned)h)<<16);
}
__device__ __forceinline__ float rrelu(float v){ return v>=0.f ? v : v*SLOPE; }

// ---- weight repack to bf16 (k = tap*IC + i for convs; bias panels [o][32]) ----
__global__ __launch_bounds__(256) void prep_w(
  const float* __restrict__ w0, const float* __restrict__ w1, const float* __restrict__ w2,
  const float* __restrict__ pw0, const float* __restrict__ pw1,
  const float* __restrict__ pb0, const float* __restrict__ pb1,
  unsigned short* __restrict__ w0e, unsigned short* __restrict__ w1e, unsigned short* __restrict__ w2e,
  unsigned short* __restrict__ pw0b, unsigned short* __restrict__ pw1b,
  unsigned short* __restrict__ pb0e, unsigned short* __restrict__ pb1e)
{
  int idx = blockIdx.x*256 + threadIdx.x;
  if (idx < 8192){ int oc=idx>>6, k=idx&63, tap=k>>5, i=k&31;
    w0e[idx] = f2bf(w0[(oc*32+i)*2+tap]); return; }
  idx -= 8192;
  if (idx < 32768){ int oc=idx>>8, k=idx&255, tap=k>>7, i=k&127;
    w1e[idx] = f2bf(w1[(oc*128+i)*2+tap]); return; }
  idx -= 32768;
  if (idx < 32768){ int oc=idx>>8, k=idx&255, tap=k>>7, i=k&127;
    w2e[idx] = f2bf(w2[(oc*128+i)*2+tap]); return; }
  idx -= 32768;
  if (idx < 262144){ pw0b[idx] = f2bf(pw0[idx]); return; }
  idx -= 262144;
  if (idx < 131072){ pw1b[idx] = f2bf(pw1[idx]); return; }
  idx -= 131072;
  if (idx < 8192){ int o=idx>>5, r=idx&31; pb0e[idx] = r<8 ? f2bf(pb0[r*256+o]) : (unsigned short)0; return; }
  idx -= 8192;
  if (idx < 2048){ int o=idx>>5, r=idx&31; pb1e[idx] = r<8 ? f2bf(pb1[r*64+o]) : (unsigned short)0; return; }
}

// ---- x (B,32,4096) fp32 -> xt (B,4111,32) bf16, 15 zero-pad rows in front ----
__global__ __launch_bounds__(64) void prep_xt(const float* __restrict__ x,
                                              unsigned short* __restrict__ xt)
{
  __shared__ float s[32][64];
  const int b = blockIdx.y, j0 = blockIdx.x*64, l = threadIdx.x;
  #pragma unroll 4
  for (int i=0;i<32;i++){
    int p = j0 + l - 15;
    s[i][l] = (p>=0 && p<4096) ? x[((size_t)b*32+i)*4096+p] : 0.f;
  }
  __syncthreads();
  const int j = j0 + l;
  if (j < NX){
    unsigned tmp[16];
    #pragma unroll
    for (int q=0;q<16;q++)
      tmp[q] = (unsigned)f2bf(s[2*q][l]) | ((unsigned)f2bf(s[2*q+1][l])<<16);
    ui4* dst = (ui4*)(xt + ((size_t)b*NX + j)*32);
    #pragma unroll
    for (int q=0;q<4;q++){ ui4 v={tmp[4*q],tmp[4*q+1],tmp[4*q+2],tmp[4*q+3]}; dst[q]=v; }
  }
}

// ---- dilated k=2 conv as MFMA GEMM: o64-block, t64, 4 waves x t16.
// Weights K-half staged in LDS; output restaged -> full 128B-line writes.
template<int IC, int DIL, int NIN, int NOUT>
__global__ __launch_bounds__(256) void conv_g(
    const unsigned short* __restrict__ act,   // [8][NIN][IC]
    const unsigned short* __restrict__ wgt,   // [128][2*IC]
    const float* __restrict__ bias,           // [128]
    unsigned short* __restrict__ outp)        // [8][NOUT][128]
{
  constexpr int KT   = 2*IC;
  constexpr int NK   = KT/32;
  constexpr int NH   = (KT > 128) ? 2 : 1;
  constexpr int KPH  = KT / NH;
  constexpr int NKH  = KPH/32;
  constexpr int HRB  = KPH*2;
  constexpr int HCPR = HRB/16;
  __shared__ __align__(16) char wsm[64*HRB];
  __shared__ __align__(16) char outs[64*128];

  const int tid = threadIdx.x;
  const int b = blockIdx.z, ob = blockIdx.y, tb = blockIdx.x*64;
  const int o0g = ob*64;
  const int wid = tid>>6, l = tid&63, lo = l&15, hi = l>>4;

  bf16x8 bfr[NK];
  {
    const int tg = tb + wid*16 + lo;
    const int te = tg < NOUT ? tg : NOUT-1;
    #pragma unroll
    for (int kk=0;kk<NK;kk++){
      int k = kk*32 + hi*8;
      int tap = (k >= IC) ? 1 : 0;
      int off = k - tap*IC;
      bfr[kk] = *(const bf16x8*)(act + ((size_t)b*NIN + te + tap*DIL)*IC + off);
    }
  }

  f32x4 acc[4];
  #pragma unroll
  for (int m=0;m<4;m++) acc[m] = (f32x4){0.f,0.f,0.f,0.f};

  #pragma unroll
  for (int h=0; h<NH; ++h){
    __syncthreads();
    for (int c = tid; c < 64*HCPR; c += 256){
      int row = c / HCPR, cc = c % HCPR;
      ui4 v = *(const ui4*)((const char*)wgt + (size_t)(o0g+row)*KT*2 + h*HRB + cc*16);
      *(ui4*)(wsm + row*HRB + ((cc*16) ^ ((row&7)<<4))) = v;
    }
    __syncthreads();
    #pragma unroll
    for (int kk=0;kk<NKH;kk++){
      #pragma unroll
      for (int m=0;m<4;m++){
        int row = m*16 + lo;
        bf16x8 af = *(const bf16x8*)(wsm + row*HRB + ((kk*64+hi*16) ^ ((row&7)<<4)));
        acc[m] = __builtin_amdgcn_mfma_f32_16x16x32_bf16(af, bfr[h*NKH+kk], acc[m], 0,0,0);
      }
    }
  }
  __syncthreads();
  #pragma unroll
  for (int m=0;m<4;m++){
    const int ol = m*16 + hi*4;
    float b0v = bias[o0g+ol+0], b1v = bias[o0g+ol+1], b2v = bias[o0g+ol+2], b3v = bias[o0g+ol+3];
    int tl = wid*16 + lo;
    us4 v;
    v.x = f2bf(rrelu(acc[m][0] + b0v));
    v.y = f2bf(rrelu(acc[m][1] + b1v));
    v.z = f2bf(rrelu(acc[m][2] + b2v));
    v.w = f2bf(rrelu(acc[m][3] + b3v));
    *(us4*)(outs + tl*128 + ((ol*2) ^ ((tl&7)<<4))) = v;
  }
  __syncthreads();
  #pragma unroll
  for (int i=0;i<2;i++){
    int c = tid + i*256;
    int row = c>>3, cc = c&7;
    if (tb + row < NOUT){
      ui4 v = *(const ui4*)(outs + row*128 + ((cc*16) ^ ((row&7)<<4)));
      *(ui4*)(outp + ((size_t)b*NOUT + tb + row)*128 + o0g + cc*8) = v;
    }
  }
}

// ---- conv3(128->8,d=8) + rrelu + log-softmax + gumbel-softmax (fp32 math) ----
__global__ __launch_bounds__(64) void gumbel_g(
  const unsigned short* __restrict__ h2t,  // [8][N2][128] bf16
  const float* __restrict__ w3, const float* __restrict__ b3,
  const float* __restrict__ u,
  float* __restrict__ genz,                // [8][8][4096] fp32 (output 2)
  unsigned short* __restrict__ zt)         // [8][4096][32] bf16 (z padded to K=32)
{
  __shared__ unsigned hs[72][66];
  const int b = blockIdx.y, t0 = blockIdx.x*64, l = threadIdx.x;
  const unsigned* src = (const unsigned*)(h2t + ((size_t)b*N2 + t0)*128);
  for (int e=l; e<72*64; e+=64) hs[e>>6][e&63] = src[e];
  __syncthreads();

  float acc[8];
  #pragma unroll
  for (int r=0;r<8;r++) acc[r]=b3[r];
  for (int i2=0;i2<64;i2++){
    unsigned a0 = hs[l][i2], a1 = hs[l+8][i2];
    float v00 = bf2f(a0&0xffff), v01 = bf2f(a0>>16);
    float v10 = bf2f(a1&0xffff), v11 = bf2f(a1>>16);
    const int i = 2*i2;
    #pragma unroll
    for (int r=0;r<8;r++){
      acc[r] = fmaf(w3[(r*128+i)*2],     v00, acc[r]);
      acc[r] = fmaf(w3[(r*128+i)*2+1],   v10, acc[r]);
      acc[r] = fmaf(w3[(r*128+i+1)*2],   v01, acc[r]);
      acc[r] = fmaf(w3[(r*128+i+1)*2+1], v11, acc[r]);
    }
  }
  float m = -1e30f;
  #pragma unroll
  for (int r=0;r<8;r++){ acc[r] = rrelu(acc[r]); m = fmaxf(m, acc[r]); }
  float s = 0.f;
  #pragma unroll
  for (int r=0;r<8;r++) s += __expf(acc[r]-m);
  const float lse = m + __logf(s);
  const int t = t0 + l;
  const float* ub = u + ((size_t)b*4096 + t)*8;
  float y[8], m2 = -1e30f;
  #pragma unroll
  for (int r=0;r<8;r++){
    float g = -__logf(-__logf(ub[r]));
    y[r] = (acc[r] - lse + g)*10.f;
    m2 = fmaxf(m2, y[r]);
  }
  float s2 = 0.f;
  #pragma unroll
  for (int r=0;r<8;r++){ y[r] = __expf(y[r]-m2); s2 += y[r]; }
  const float inv = 1.f/s2;
  #pragma unroll
  for (int r=0;r<8;r++){
    y[r] *= inv;
    genz[((size_t)b*8+r)*4096 + t] = y[r];
  }
  ui4 zp = { (unsigned)f2bf(y[0]) | ((unsigned)f2bf(y[1])<<16),
             (unsigned)f2bf(y[2]) | ((unsigned)f2bf(y[3])<<16),
             (unsigned)f2bf(y[4]) | ((unsigned)f2bf(y[5])<<16),
             (unsigned)f2bf(y[6]) | ((unsigned)f2bf(y[7])<<16) };
  ui4 zz = {0,0,0,0};
  ui4* zd = (ui4*)(zt + ((size_t)b*4096 + t)*32);
  zd[0]=zp; zd[1]=zz; zd[2]=zz; zd[3]=zz;
}

// ---- FUSED MoE (layer0 + layer1 + output transforms), one block per (b,t64).
// 512 thr = 8 waves. Phase 1: wave w = o32 (m2) x t64 (n4), A streamed
// global->reg, zero r-loop barriers; hid tile -> LDS (bf16, swizzled).
// Phase 2: wave = (o16 quarter) x (K-half 128): m1 n4, B-frags cached in
// registers (16 LDS reads/wave), A streamed; f32 k-reduce via reused LDS.
__global__ __launch_bounds__(512) void moe_f(
  const unsigned short* __restrict__ h2t,  // [8][N2][128]
  const float* __restrict__ genz,
  const unsigned short* __restrict__ zt,   // [8][4096][32]
  const unsigned short* __restrict__ pw0b, // [8][256][128]
  const unsigned short* __restrict__ pb0e, // [256][32]
  const unsigned short* __restrict__ pw1b, // [8][64][256]
  const unsigned short* __restrict__ pb1e, // [64][32]
  float* __restrict__ out)
{
  __shared__ __align__(16) char pres[16384];   // [t64][256B] swz; reused as f32 red
  __shared__ __align__(16) char hids[32768];   // [t64][512B] swz (hid tile bf16)
  __shared__ float zl[512];                    // [8][64]

  const int b = blockIdx.y, tb = blockIdx.x*64;
  const int tid = threadIdx.x;
  zl[tid] = genz[((size_t)b*8 + (tid>>6))*4096 + tb + (tid&63)];
  {
    const char* src = (const char*)(h2t + ((size_t)b*N2 + tb + 8)*128);
    #pragma unroll
    for (int i=0;i<2;i++){
      int c = tid + i*512, row = c>>4, cc = c&15;
      ui4 v = *(const ui4*)(src + row*256 + cc*16);
      *(ui4*)(pres + row*256 + ((cc*16) ^ ((row&7)<<4))) = v;
    }
  }
  __syncthreads();

  const int wid = tid>>6, l = tid&63, lo = l&15, hi = l>>4;

  // ================= phase 1: hid = sum_r z_r (W0_r @ pre + b0_r) =========
  const int ow = wid*32;                       // wave's o32 (8 waves = o256)
  bf16x8 bfr[4][4];
  #pragma unroll
  for (int n=0;n<4;n++){
    int tl = n*16 + lo;
    #pragma unroll
    for (int kk=0;kk<4;kk++)
      bfr[n][kk] = *(const bf16x8*)(pres + tl*256 + ((kk*64 + hi*16) ^ ((tl&7)<<4)));
  }
  bf16x8 zfr[4];
  #pragma unroll
  for (int n=0;n<4;n++)
    zfr[n] = *(const bf16x8*)(zt + ((size_t)b*4096 + tb + n*16 + lo)*32 + hi*8);

  f32x4 acc[2][4];
  #pragma unroll
  for (int m=0;m<2;m++){
    bf16x8 pf = *(const bf16x8*)(pb0e + (size_t)(ow + m*16 + lo)*32 + hi*8);
    #pragma unroll
    for (int n=0;n<4;n++)
      acc[m][n] = __builtin_amdgcn_mfma_f32_16x16x32_bf16(pf, zfr[n], (f32x4){0.f,0.f,0.f,0.f}, 0,0,0);
  }

  const unsigned short* abase0 = pw0b + (size_t)(ow + lo)*128 + hi*8;
  #pragma unroll
  for (int r=0;r<8;r++){
    f32x4 ar[2][4];
    #pragma unroll
    for (int m=0;m<2;m++)
      #pragma unroll
      for (int n=0;n<4;n++) ar[m][n] = (f32x4){0.f,0.f,0.f,0.f};
    #pragma unroll
    for (int kk=0;kk<4;kk++){
      bf16x8 A0 = *(const bf16x8*)(abase0 + (size_t)r*32768 + kk*32);
      bf16x8 A1 = *(const bf16x8*)(abase0 + (size_t)r*32768 + 2048 + kk*32);
      #pragma unroll
      for (int n=0;n<4;n++){
        ar[0][n] = __builtin_amdgcn_mfma_f32_16x16x32_bf16(A0, bfr[n][kk], ar[0][n], 0,0,0);
        ar[1][n] = __builtin_amdgcn_mfma_f32_16x16x32_bf16(A1, bfr[n][kk], ar[1][n], 0,0,0);
      }
    }
    #pragma unroll
    for (int n=0;n<4;n++){
      float zv = zl[r*64 + n*16 + lo];
      #pragma unroll
      for (int m=0;m<2;m++)
        #pragma unroll
        for (int c2=0;c2<4;c2++)
          acc[m][n][c2] = fmaf(zv, ar[m][n][c2], acc[m][n][c2]);
    }
  }

  // hid tile -> LDS (bf16, [t64][512B] swizzled)
  #pragma unroll
  for (int m=0;m<2;m++){
    int ol2 = (ow + m*16 + hi*4)*2;
    #pragma unroll
    for (int n=0;n<4;n++){
      int tl = n*16 + lo;
      us4 v;
      v.x=f2bf(acc[m][n][0]); v.y=f2bf(acc[m][n][1]);
      v.z=f2bf(acc[m][n][2]); v.w=f2bf(acc[m][n][3]);
      *(us4*)(hids + tl*512 + (ol2 ^ ((tl&7)<<4))) = v;
    }
  }
  __syncthreads();

  // ================= phase 2: out = transforms( sum_r z_r (W1_r @ hid + b1_r) )
  const int kh = wid & 1, oq = wid >> 1;
  const int ow2 = oq*16;

  bf16x8 bfr2[4][4];                           // B frags: t64 x K-half(128)
  #pragma unroll
  for (int n=0;n<4;n++){
    int tl = n*16 + lo;
    #pragma unroll
    for (int kk=0;kk<4;kk++)
      bfr2[n][kk] = *(const bf16x8*)(hids + tl*512 + ((kh*256 + kk*64 + hi*16) ^ ((tl&7)<<4)));
  }
  f32x4 acc2[4];
  if (kh == 0){
    bf16x8 pf = *(const bf16x8*)(pb1e + (size_t)(ow2 + lo)*32 + hi*8);
    #pragma unroll
    for (int n=0;n<4;n++)
      acc2[n] = __builtin_amdgcn_mfma_f32_16x16x32_bf16(pf, zfr[n], (f32x4){0.f,0.f,0.f,0.f}, 0,0,0);
  } else {
    #pragma unroll
    for (int n=0;n<4;n++) acc2[n] = (f32x4){0.f,0.f,0.f,0.f};
  }

  const unsigned short* abase1 = pw1b + (size_t)(ow2 + lo)*256 + kh*128 + hi*8;
  #pragma unroll
  for (int r=0;r<8;r++){
    f32x4 ar2[4];
    #pragma unroll
    for (int n=0;n<4;n++) ar2[n] = (f32x4){0.f,0.f,0.f,0.f};
    #pragma unroll
    for (int kk=0;kk<4;kk++){
      bf16x8 A2 = *(const bf16x8*)(abase1 + (size_t)r*16384 + kk*32);
      #pragma unroll
      for (int n=0;n<4;n++)
        ar2[n] = __builtin_amdgcn_mfma_f32_16x16x32_bf16(A2, bfr2[n][kk], ar2[n], 0,0,0);
    }
    #pragma unroll
    for (int n=0;n<4;n++){
      float zv = zl[r*64 + n*16 + lo];
      #pragma unroll
      for (int c2=0;c2<4;c2++)
        acc2[n][c2] = fmaf(zv, ar2[n][c2], acc2[n][c2]);
    }
  }

  // k-reduce via pres reused as f32 red[o64][t64]
  float* red = (float*)pres;
  if (kh == 1){
    #pragma unroll
    for (int n=0;n<4;n++)
      #pragma unroll
      for (int c2=0;c2<4;c2++)
        red[(ow2 + hi*4 + c2)*64 + n*16 + lo] = acc2[n][c2];
  }
  __syncthreads();
  if (kh == 0){
    #pragma unroll
    for (int n=0;n<4;n++){
      int t = tb + n*16 + lo;
      #pragma unroll
      for (int c2=0;c2<4;c2++){
        int o = ow2 + hi*4 + c2;
        float v = acc2[n][c2] + red[o*64 + n*16 + lo];
        if (o < 32)
          out[((size_t)b*32 + o)*4096 + t] = v;
        else {
          float e = __expf(2.f*v);
          float th = 1.f - 2.f/(e+1.f);
          out[(size_t)1048576 + ((size_t)b*32 + (o-32))*4096 + t] = 0.5f + 0.5f*th + 0.001f;
        }
      }
    }
  }
}

extern "C" void kernel_launch(void* const* d_in, const int* in_sizes, int n_in,
                              void* d_out, int out_size, void* d_ws, size_t ws_size,
                              hipStream_t stream) {
  const float* x   = (const float*)d_in[0];
  const float* u   = (const float*)d_in[1];
  const float* w0  = (const float*)d_in[2];
  const float* b0  = (const float*)d_in[3];
  const float* w1  = (const float*)d_in[4];
  const float* b1  = (const float*)d_in[5];
  const float* w2  = (const float*)d_in[6];
  const float* b2  = (const float*)d_in[7];
  const float* w3  = (const float*)d_in[8];
  const float* b3  = (const float*)d_in[9];
  const float* pw0 = (const float*)d_in[10];
  const float* pb0 = (const float*)d_in[11];
  const float* pw1 = (const float*)d_in[12];
  const float* pb1 = (const float*)d_in[13];

  float* out  = (float*)d_out;
  float* genz = out + (size_t)2*8*32*4096;

  char* p = (char*)d_ws;
  unsigned short* xt   = (unsigned short*)p; p += 2104832;   // 8*4111*32
  unsigned short* h0t  = (unsigned short*)p; p += 8417280;   // 8*4110*128
  unsigned short* h1t  = (unsigned short*)p; p += 8413184;   // 8*4108*128
  unsigned short* h2t  = (unsigned short*)p; p += 8404992;   // 8*4104*128
  unsigned short* ztb  = (unsigned short*)p; p += 2097152;   // 8*4096*32
  unsigned short* w0e  = (unsigned short*)p; p += 16384;
  unsigned short* w1e  = (unsigned short*)p; p += 65536;
  unsigned short* w2e  = (unsigned short*)p; p += 65536;
  unsigned short* pw0b = (unsigned short*)p; p += 524288;
  unsigned short* pw1b = (unsigned short*)p; p += 262144;
  unsigned short* pb0e = (unsigned short*)p; p += 16384;
  unsigned short* pb1e = (unsigned short*)p; p += 4096;

  prep_w<<<1864, 256, 0, stream>>>(w0,w1,w2,pw0,pw1,pb0,pb1,
                                   w0e,w1e,w2e,pw0b,pw1b,pb0e,pb1e);
  prep_xt<<<dim3(65,8), 64, 0, stream>>>(x, xt);
  conv_g<32,1,NX,N0><<<dim3(65,2,8), 256, 0, stream>>>(xt,  w0e, b0, h0t);
  conv_g<128,2,N0,N1><<<dim3(65,2,8), 256, 0, stream>>>(h0t, w1e, b1, h1t);
  conv_g<128,4,N1,N2><<<dim3(65,2,8), 256, 0, stream>>>(h1t, w2e, b2, h2t);
  gumbel_g<<<dim3(64,8), 64, 0, stream>>>(h2t, w3, b3, u, genz, ztb);
  moe_f<<<dim3(64,8), 512, 0, stream>>>(h2t, genz, ztb, pw0b, pb0e, pw1b, pb1e, out);
}

// Round 19
// 141.636 us; speedup vs baseline: 1.1417x; 1.1417x over previous
//
#include <hip/hip_runtime.h>
#include <math.h>

typedef __attribute__((ext_vector_type(8))) short bf16x8;   // 8 bf16 = 4 VGPR
typedef __attribute__((ext_vector_type(4))) float f32x4;    // MFMA acc
struct __align__(8)  us4 { unsigned short x,y,z,w; };
struct __align__(16) ui4 { unsigned x,y,z,w; };

#define SLOPE 0.2291666666666667f
constexpr int N0=4110, N1=4108, N2=4104, NX=4111;

__device__ __forceinline__ unsigned short f2bf(float f){
  unsigned u = __float_as_uint(f);
  u = (u + 0x7FFF + ((u>>16)&1)) >> 16;   // RNE
  return (unsigned short)u;
}
__device__ __forceinline__ float bf2f(unsigned short h){
  return __uint_as_float(((unsigned)h)<<16);
}
__device__ __forceinline__ float rrelu(float v){ return v>=0.f ? v : v*SLOPE; }

// ---- weight repack to bf16 (k = tap*IC + i for convs; bias panels [o][32]) ----
__global__ __launch_bounds__(256) void prep_w(
  const float* __restrict__ w0, const float* __restrict__ w1, const float* __restrict__ w2,
  const float* __restrict__ pw0, const float* __restrict__ pw1,
  const float* __restrict__ pb0, const float* __restrict__ pb1,
  unsigned short* __restrict__ w0e, unsigned short* __restrict__ w1e, unsigned short* __restrict__ w2e,
  unsigned short* __restrict__ pw0b, unsigned short* __restrict__ pw1b,
  unsigned short* __restrict__ pb0e, unsigned short* __restrict__ pb1e)
{
  int idx = blockIdx.x*256 + threadIdx.x;
  if (idx < 8192){ int oc=idx>>6, k=idx&63, tap=k>>5, i=k&31;
    w0e[idx] = f2bf(w0[(oc*32+i)*2+tap]); return; }
  idx -= 8192;
  if (idx < 32768){ int oc=idx>>8, k=idx&255, tap=k>>7, i=k&127;
    w1e[idx] = f2bf(w1[(oc*128+i)*2+tap]); return; }
  idx -= 32768;
  if (idx < 32768){ int oc=idx>>8, k=idx&255, tap=k>>7, i=k&127;
    w2e[idx] = f2bf(w2[(oc*128+i)*2+tap]); return; }
  idx -= 32768;
  if (idx < 262144){ pw0b[idx] = f2bf(pw0[idx]); return; }
  idx -= 262144;
  if (idx < 131072){ pw1b[idx] = f2bf(pw1[idx]); return; }
  idx -= 131072;
  if (idx < 8192){ int o=idx>>5, r=idx&31; pb0e[idx] = r<8 ? f2bf(pb0[r*256+o]) : (unsigned short)0; return; }
  idx -= 8192;
  if (idx < 2048){ int o=idx>>5, r=idx&31; pb1e[idx] = r<8 ? f2bf(pb1[r*64+o]) : (unsigned short)0; return; }
}

// ---- x (B,32,4096) fp32 -> xt (B,4111,32) bf16, 15 zero-pad rows in front ----
__global__ __launch_bounds__(64) void prep_xt(const float* __restrict__ x,
                                              unsigned short* __restrict__ xt)
{
  __shared__ float s[32][64];
  const int b = blockIdx.y, j0 = blockIdx.x*64, l = threadIdx.x;
  #pragma unroll 4
  for (int i=0;i<32;i++){
    int p = j0 + l - 15;
    s[i][l] = (p>=0 && p<4096) ? x[((size_t)b*32+i)*4096+p] : 0.f;
  }
  __syncthreads();
  const int j = j0 + l;
  if (j < NX){
    unsigned tmp[16];
    #pragma unroll
    for (int q=0;q<16;q++)
      tmp[q] = (unsigned)f2bf(s[2*q][l]) | ((unsigned)f2bf(s[2*q+1][l])<<16);
    ui4* dst = (ui4*)(xt + ((size_t)b*NX + j)*32);
    #pragma unroll
    for (int q=0;q<4;q++){ ui4 v={tmp[4*q],tmp[4*q+1],tmp[4*q+2],tmp[4*q+3]}; dst[q]=v; }
  }
}

// ---- dilated k=2 conv as MFMA GEMM: o64-block, t64, 4 waves x t16.
// Weights K-half staged in LDS; output restaged -> full 128B-line writes.
template<int IC, int DIL, int NIN, int NOUT>
__global__ __launch_bounds__(256) void conv_g(
    const unsigned short* __restrict__ act,   // [8][NIN][IC]
    const unsigned short* __restrict__ wgt,   // [128][2*IC]
    const float* __restrict__ bias,           // [128]
    unsigned short* __restrict__ outp)        // [8][NOUT][128]
{
  constexpr int KT   = 2*IC;
  constexpr int NK   = KT/32;
  constexpr int NH   = (KT > 128) ? 2 : 1;
  constexpr int KPH  = KT / NH;
  constexpr int NKH  = KPH/32;
  constexpr int HRB  = KPH*2;
  constexpr int HCPR = HRB/16;
  __shared__ __align__(16) char wsm[64*HRB];
  __shared__ __align__(16) char outs[64*128];

  const int tid = threadIdx.x;
  const int b = blockIdx.z, ob = blockIdx.y, tb = blockIdx.x*64;
  const int o0g = ob*64;
  const int wid = tid>>6, l = tid&63, lo = l&15, hi = l>>4;

  bf16x8 bfr[NK];
  {
    const int tg = tb + wid*16 + lo;
    const int te = tg < NOUT ? tg : NOUT-1;
    #pragma unroll
    for (int kk=0;kk<NK;kk++){
      int k = kk*32 + hi*8;
      int tap = (k >= IC) ? 1 : 0;
      int off = k - tap*IC;
      bfr[kk] = *(const bf16x8*)(act + ((size_t)b*NIN + te + tap*DIL)*IC + off);
    }
  }

  f32x4 acc[4];
  #pragma unroll
  for (int m=0;m<4;m++) acc[m] = (f32x4){0.f,0.f,0.f,0.f};

  #pragma unroll
  for (int h=0; h<NH; ++h){
    __syncthreads();
    for (int c = tid; c < 64*HCPR; c += 256){
      int row = c / HCPR, cc = c % HCPR;
      ui4 v = *(const ui4*)((const char*)wgt + (size_t)(o0g+row)*KT*2 + h*HRB + cc*16);
      *(ui4*)(wsm + row*HRB + ((cc*16) ^ ((row&7)<<4))) = v;
    }
    __syncthreads();
    #pragma unroll
    for (int kk=0;kk<NKH;kk++){
      #pragma unroll
      for (int m=0;m<4;m++){
        int row = m*16 + lo;
        bf16x8 af = *(const bf16x8*)(wsm + row*HRB + ((kk*64+hi*16) ^ ((row&7)<<4)));
        acc[m] = __builtin_amdgcn_mfma_f32_16x16x32_bf16(af, bfr[h*NKH+kk], acc[m], 0,0,0);
      }
    }
  }
  __syncthreads();
  #pragma unroll
  for (int m=0;m<4;m++){
    const int ol = m*16 + hi*4;
    float b0v = bias[o0g+ol+0], b1v = bias[o0g+ol+1], b2v = bias[o0g+ol+2], b3v = bias[o0g+ol+3];
    int tl = wid*16 + lo;
    us4 v;
    v.x = f2bf(rrelu(acc[m][0] + b0v));
    v.y = f2bf(rrelu(acc[m][1] + b1v));
    v.z = f2bf(rrelu(acc[m][2] + b2v));
    v.w = f2bf(rrelu(acc[m][3] + b3v));
    *(us4*)(outs + tl*128 + ((ol*2) ^ ((tl&7)<<4))) = v;
  }
  __syncthreads();
  #pragma unroll
  for (int i=0;i<2;i++){
    int c = tid + i*256;
    int row = c>>3, cc = c&7;
    if (tb + row < NOUT){
      ui4 v = *(const ui4*)(outs + row*128 + ((cc*16) ^ ((row&7)<<4)));
      *(ui4*)(outp + ((size_t)b*NOUT + tb + row)*128 + o0g + cc*8) = v;
    }
  }
}

// ---- conv3(128->8,d=8) + rrelu + log-softmax + gumbel-softmax (fp32 math) ----
__global__ __launch_bounds__(64) void gumbel_g(
  const unsigned short* __restrict__ h2t,  // [8][N2][128] bf16
  const float* __restrict__ w3, const float* __restrict__ b3,
  const float* __restrict__ u,
  float* __restrict__ genz,                // [8][8][4096] fp32 (output 2)
  unsigned short* __restrict__ zt)         // [8][4096][32] bf16 (z padded to K=32)
{
  __shared__ unsigned hs[72][66];
  const int b = blockIdx.y, t0 = blockIdx.x*64, l = threadIdx.x;
  const unsigned* src = (const unsigned*)(h2t + ((size_t)b*N2 + t0)*128);
  for (int e=l; e<72*64; e+=64) hs[e>>6][e&63] = src[e];
  __syncthreads();

  float acc[8];
  #pragma unroll
  for (int r=0;r<8;r++) acc[r]=b3[r];
  for (int i2=0;i2<64;i2++){
    unsigned a0 = hs[l][i2], a1 = hs[l+8][i2];
    float v00 = bf2f(a0&0xffff), v01 = bf2f(a0>>16);
    float v10 = bf2f(a1&0xffff), v11 = bf2f(a1>>16);
    const int i = 2*i2;
    #pragma unroll
    for (int r=0;r<8;r++){
      acc[r] = fmaf(w3[(r*128+i)*2],     v00, acc[r]);
      acc[r] = fmaf(w3[(r*128+i)*2+1],   v10, acc[r]);
      acc[r] = fmaf(w3[(r*128+i+1)*2],   v01, acc[r]);
      acc[r] = fmaf(w3[(r*128+i+1)*2+1], v11, acc[r]);
    }
  }
  float m = -1e30f;
  #pragma unroll
  for (int r=0;r<8;r++){ acc[r] = rrelu(acc[r]); m = fmaxf(m, acc[r]); }
  float s = 0.f;
  #pragma unroll
  for (int r=0;r<8;r++) s += __expf(acc[r]-m);
  const float lse = m + __logf(s);
  const int t = t0 + l;
  const float* ub = u + ((size_t)b*4096 + t)*8;
  float y[8], m2 = -1e30f;
  #pragma unroll
  for (int r=0;r<8;r++){
    float g = -__logf(-__logf(ub[r]));
    y[r] = (acc[r] - lse + g)*10.f;
    m2 = fmaxf(m2, y[r]);
  }
  float s2 = 0.f;
  #pragma unroll
  for (int r=0;r<8;r++){ y[r] = __expf(y[r]-m2); s2 += y[r]; }
  const float inv = 1.f/s2;
  #pragma unroll
  for (int r=0;r<8;r++){
    y[r] *= inv;
    genz[((size_t)b*8+r)*4096 + t] = y[r];
  }
  ui4 zp = { (unsigned)f2bf(y[0]) | ((unsigned)f2bf(y[1])<<16),
             (unsigned)f2bf(y[2]) | ((unsigned)f2bf(y[3])<<16),
             (unsigned)f2bf(y[4]) | ((unsigned)f2bf(y[5])<<16),
             (unsigned)f2bf(y[6]) | ((unsigned)f2bf(y[7])<<16) };
  ui4 zz = {0,0,0,0};
  ui4* zd = (ui4*)(zt + ((size_t)b*4096 + t)*32);
  zd[0]=zp; zd[1]=zz; zd[2]=zz; zd[3]=zz;
}

// ---- FUSED MoE v2 (spill-free): B-fragments re-read from LDS inside the
// r-loops (no register B arrays). One block per (b,t64), 512 thr = 8 waves.
// Phase 1: wave = o32(m2) x t64(n4), A global->reg, hid -> LDS (swizzled).
// Phase 2: wave = o16 x K-half, A global->reg, f32 k-reduce via reused LDS.
__global__ __launch_bounds__(512) void moe_f(
  const unsigned short* __restrict__ h2t,  // [8][N2][128]
  const float* __restrict__ genz,
  const unsigned short* __restrict__ zt,   // [8][4096][32]
  const unsigned short* __restrict__ pw0b, // [8][256][128]
  const unsigned short* __restrict__ pb0e, // [256][32]
  const unsigned short* __restrict__ pw1b, // [8][64][256]
  const unsigned short* __restrict__ pb1e, // [64][32]
  float* __restrict__ out)
{
  __shared__ __align__(16) char pres[16384];   // [t64][256B] swz; reused as f32 red
  __shared__ __align__(16) char hids[32768];   // [t64][512B] swz (hid tile bf16)
  __shared__ float zl[512];                    // [8][64]

  const int b = blockIdx.y, tb = blockIdx.x*64;
  const int tid = threadIdx.x;
  zl[tid] = genz[((size_t)b*8 + (tid>>6))*4096 + tb + (tid&63)];
  {
    const char* src = (const char*)(h2t + ((size_t)b*N2 + tb + 8)*128);
    #pragma unroll
    for (int i=0;i<2;i++){
      int c = tid + i*512, row = c>>4, cc = c&15;
      ui4 v = *(const ui4*)(src + row*256 + cc*16);
      *(ui4*)(pres + row*256 + ((cc*16) ^ ((row&7)<<4))) = v;
    }
  }
  __syncthreads();

  const int wid = tid>>6, l = tid&63, lo = l&15, hi = l>>4;

  // ================= phase 1: hid = sum_r z_r (W0_r @ pre + b0_r) =========
  const int ow = wid*32;                       // wave's o32 (8 waves = o256)
  f32x4 acc[2][4];
  #pragma unroll
  for (int m=0;m<2;m++){
    bf16x8 pf = *(const bf16x8*)(pb0e + (size_t)(ow + m*16 + lo)*32 + hi*8);
    #pragma unroll
    for (int n=0;n<4;n++){
      bf16x8 zf = *(const bf16x8*)(zt + ((size_t)b*4096 + tb + n*16 + lo)*32 + hi*8);
      acc[m][n] = __builtin_amdgcn_mfma_f32_16x16x32_bf16(pf, zf, (f32x4){0.f,0.f,0.f,0.f}, 0,0,0);
    }
  }

  const unsigned short* abase0 = pw0b + (size_t)(ow + lo)*128 + hi*8;
  for (int r=0;r<8;r++){
    f32x4 ar[2][4];
    #pragma unroll
    for (int m=0;m<2;m++)
      #pragma unroll
      for (int n=0;n<4;n++) ar[m][n] = (f32x4){0.f,0.f,0.f,0.f};
    #pragma unroll
    for (int kk=0;kk<4;kk++){
      bf16x8 A0 = *(const bf16x8*)(abase0 + (size_t)r*32768 + kk*32);
      bf16x8 A1 = *(const bf16x8*)(abase0 + (size_t)r*32768 + 2048 + kk*32);
      #pragma unroll
      for (int n=0;n<4;n++){
        int tl = n*16 + lo;
        bf16x8 bf = *(const bf16x8*)(pres + tl*256 + ((kk*64 + hi*16) ^ ((tl&7)<<4)));
        ar[0][n] = __builtin_amdgcn_mfma_f32_16x16x32_bf16(A0, bf, ar[0][n], 0,0,0);
        ar[1][n] = __builtin_amdgcn_mfma_f32_16x16x32_bf16(A1, bf, ar[1][n], 0,0,0);
      }
    }
    #pragma unroll
    for (int n=0;n<4;n++){
      float zv = zl[r*64 + n*16 + lo];
      #pragma unroll
      for (int m=0;m<2;m++)
        #pragma unroll
        for (int c2=0;c2<4;c2++)
          acc[m][n][c2] = fmaf(zv, ar[m][n][c2], acc[m][n][c2]);
    }
  }

  // hid tile -> LDS (bf16, [t64][512B] swizzled)
  #pragma unroll
  for (int m=0;m<2;m++){
    int ol2 = (ow + m*16 + hi*4)*2;
    #pragma unroll
    for (int n=0;n<4;n++){
      int tl = n*16 + lo;
      us4 v;
      v.x=f2bf(acc[m][n][0]); v.y=f2bf(acc[m][n][1]);
      v.z=f2bf(acc[m][n][2]); v.w=f2bf(acc[m][n][3]);
      *(us4*)(hids + tl*512 + (ol2 ^ ((tl&7)<<4))) = v;
    }
  }
  __syncthreads();

  // ================= phase 2: out = transforms( sum_r z_r (W1_r @ hid + b1_r) )
  const int kh = wid & 1, oq = wid >> 1;
  const int ow2 = oq*16;

  f32x4 acc2[4];
  if (kh == 0){
    bf16x8 pf = *(const bf16x8*)(pb1e + (size_t)(ow2 + lo)*32 + hi*8);
    #pragma unroll
    for (int n=0;n<4;n++){
      bf16x8 zf = *(const bf16x8*)(zt + ((size_t)b*4096 + tb + n*16 + lo)*32 + hi*8);
      acc2[n] = __builtin_amdgcn_mfma_f32_16x16x32_bf16(pf, zf, (f32x4){0.f,0.f,0.f,0.f}, 0,0,0);
    }
  } else {
    #pragma unroll
    for (int n=0;n<4;n++) acc2[n] = (f32x4){0.f,0.f,0.f,0.f};
  }

  const unsigned short* abase1 = pw1b + (size_t)(ow2 + lo)*256 + kh*128 + hi*8;
  for (int r=0;r<8;r++){
    f32x4 ar2[4];
    #pragma unroll
    for (int n=0;n<4;n++) ar2[n] = (f32x4){0.f,0.f,0.f,0.f};
    #pragma unroll
    for (int kk=0;kk<4;kk++){
      bf16x8 A2 = *(const bf16x8*)(abase1 + (size_t)r*16384 + kk*32);
      #pragma unroll
      for (int n=0;n<4;n++){
        int tl = n*16 + lo;
        bf16x8 bf = *(const bf16x8*)(hids + tl*512 + ((kh*256 + kk*64 + hi*16) ^ ((tl&7)<<4)));
        ar2[n] = __builtin_amdgcn_mfma_f32_16x16x32_bf16(A2, bf, ar2[n], 0,0,0);
      }
    }
    #pragma unroll
    for (int n=0;n<4;n++){
      float zv = zl[r*64 + n*16 + lo];
      #pragma unroll
      for (int c2=0;c2<4;c2++)
        acc2[n][c2] = fmaf(zv, ar2[n][c2], acc2[n][c2]);
    }
  }

  // k-reduce via pres reused as f32 red[o64][t64]
  float* red = (float*)pres;
  if (kh == 1){
    #pragma unroll
    for (int n=0;n<4;n++)
      #pragma unroll
      for (int c2=0;c2<4;c2++)
        red[(ow2 + hi*4 + c2)*64 + n*16 + lo] = acc2[n][c2];
  }
  __syncthreads();
  if (kh == 0){
    #pragma unroll
    for (int n=0;n<4;n++){
      int t = tb + n*16 + lo;
      #pragma unroll
      for (int c2=0;c2<4;c2++){
        int o = ow2 + hi*4 + c2;
        float v = acc2[n][c2] + red[o*64 + n*16 + lo];
        if (o < 32)
          out[((size_t)b*32 + o)*4096 + t] = v;
        else {
          float e = __expf(2.f*v);
          float th = 1.f - 2.f/(e+1.f);
          out[(size_t)1048576 + ((size_t)b*32 + (o-32))*4096 + t] = 0.5f + 0.5f*th + 0.001f;
        }
      }
    }
  }
}

extern "C" void kernel_launch(void* const* d_in, const int* in_sizes, int n_in,
                              void* d_out, int out_size, void* d_ws, size_t ws_size,
                              hipStream_t stream) {
  const float* x   = (const float*)d_in[0];
  const float* u   = (const float*)d_in[1];
  const float* w0  = (const float*)d_in[2];
  const float* b0  = (const float*)d_in[3];
  const float* w1  = (const float*)d_in[4];
  const float* b1  = (const float*)d_in[5];
  const float* w2  = (const float*)d_in[6];
  const float* b2  = (const float*)d_in[7];
  const float* w3  = (const float*)d_in[8];
  const float* b3  = (const float*)d_in[9];
  const float* pw0 = (const float*)d_in[10];
  const float* pb0 = (const float*)d_in[11];
  const float* pw1 = (const float*)d_in[12];
  const float* pb1 = (const float*)d_in[13];

  float* out  = (float*)d_out;
  float* genz = out + (size_t)2*8*32*4096;

  char* p = (char*)d_ws;
  unsigned short* xt   = (unsigned short*)p; p += 2104832;   // 8*4111*32
  unsigned short* h0t  = (unsigned short*)p; p += 8417280;   // 8*4110*128
  unsigned short* h1t  = (unsigned short*)p; p += 8413184;   // 8*4108*128
  unsigned short* h2t  = (unsigned short*)p; p += 8404992;   // 8*4104*128
  unsigned short* ztb  = (unsigned short*)p; p += 2097152;   // 8*4096*32
  unsigned short* w0e  = (unsigned short*)p; p += 16384;
  unsigned short* w1e  = (unsigned short*)p; p += 65536;
  unsigned short* w2e  = (unsigned short*)p; p += 65536;
  unsigned short* pw0b = (unsigned short*)p; p += 524288;
  unsigned short* pw1b = (unsigned short*)p; p += 262144;
  unsigned short* pb0e = (unsigned short*)p; p += 16384;
  unsigned short* pb1e = (unsigned short*)p; p += 4096;

  prep_w<<<1864, 256, 0, stream>>>(w0,w1,w2,pw0,pw1,pb0,pb1,
                                   w0e,w1e,w2e,pw0b,pw1b,pb0e,pb1e);
  prep_xt<<<dim3(65,8), 64, 0, stream>>>(x, xt);
  conv_g<32,1,NX,N0><<<dim3(65,2,8), 256, 0, stream>>>(xt,  w0e, b0, h0t);
  conv_g<128,2,N0,N1><<<dim3(65,2,8), 256, 0, stream>>>(h0t, w1e, b1, h1t);
  conv_g<128,4,N1,N2><<<dim3(65,2,8), 256, 0, stream>>>(h1t, w2e, b2, h2t);
  gumbel_g<<<dim3(64,8), 64, 0, stream>>>(h2t, w3, b3, u, genz, ztb);
  moe_f<<<dim3(64,8), 512, 0, stream>>>(h2t, genz, ztb, pw0b, pb0e, pw1b, pb1e, out);
}

// Round 20
// 140.752 us; speedup vs baseline: 1.1489x; 1.0063x over previous
//
#include <hip/hip_runtime.h>
#include <math.h>

typedef __attribute__((ext_vector_type(8))) short bf16x8;   // 8 bf16 = 4 VGPR
typedef __attribute__((ext_vector_type(4))) float f32x4;    // MFMA acc
struct __align__(8)  us4 { unsigned short x,y,z,w; };
struct __align__(16) ui4 { unsigned x,y,z,w; };

#define SLOPE 0.2291666666666667f
constexpr int N0=4110, N1=4108, N2=4104, NX=4111;

__device__ __forceinline__ unsigned short f2bf(float f){
  unsigned u = __float_as_uint(f);
  u = (u + 0x7FFF + ((u>>16)&1)) >> 16;   // RNE
  return (unsigned short)u;
}
__device__ __forceinline__ float bf2f(unsigned short h){
  return __uint_as_float(((unsigned)h)<<16);
}
__device__ __forceinline__ float rrelu(float v){ return v>=0.f ? v : v*SLOPE; }

// ---- weight repack to bf16 (k = tap*IC + i for convs; bias panels [o][32]) ----
__global__ __launch_bounds__(256) void prep_w(
  const float* __restrict__ w0, const float* __restrict__ w1, const float* __restrict__ w2,
  const float* __restrict__ pw0, const float* __restrict__ pw1,
  const float* __restrict__ pb0, const float* __restrict__ pb1,
  unsigned short* __restrict__ w0e, unsigned short* __restrict__ w1e, unsigned short* __restrict__ w2e,
  unsigned short* __restrict__ pw0b, unsigned short* __restrict__ pw1b,
  unsigned short* __restrict__ pb0e, unsigned short* __restrict__ pb1e)
{
  int idx = blockIdx.x*256 + threadIdx.x;
  if (idx < 8192){ int oc=idx>>6, k=idx&63, tap=k>>5, i=k&31;
    w0e[idx] = f2bf(w0[(oc*32+i)*2+tap]); return; }
  idx -= 8192;
  if (idx < 32768){ int oc=idx>>8, k=idx&255, tap=k>>7, i=k&127;
    w1e[idx] = f2bf(w1[(oc*128+i)*2+tap]); return; }
  idx -= 32768;
  if (idx < 32768){ int oc=idx>>8, k=idx&255, tap=k>>7, i=k&127;
    w2e[idx] = f2bf(w2[(oc*128+i)*2+tap]); return; }
  idx -= 32768;
  if (idx < 262144){ pw0b[idx] = f2bf(pw0[idx]); return; }
  idx -= 262144;
  if (idx < 131072){ pw1b[idx] = f2bf(pw1[idx]); return; }
  idx -= 131072;
  if (idx < 8192){ int o=idx>>5, r=idx&31; pb0e[idx] = r<8 ? f2bf(pb0[r*256+o]) : (unsigned short)0; return; }
  idx -= 8192;
  if (idx < 2048){ int o=idx>>5, r=idx&31; pb1e[idx] = r<8 ? f2bf(pb1[r*64+o]) : (unsigned short)0; return; }
}

// ---- x (B,32,4096) fp32 -> xt (B,4111,32) bf16, 15 zero-pad rows in front ----
__global__ __launch_bounds__(64) void prep_xt(const float* __restrict__ x,
                                              unsigned short* __restrict__ xt)
{
  __shared__ float s[32][64];
  const int b = blockIdx.y, j0 = blockIdx.x*64, l = threadIdx.x;
  #pragma unroll 4
  for (int i=0;i<32;i++){
    int p = j0 + l - 15;
    s[i][l] = (p>=0 && p<4096) ? x[((size_t)b*32+i)*4096+p] : 0.f;
  }
  __syncthreads();
  const int j = j0 + l;
  if (j < NX){
    unsigned tmp[16];
    #pragma unroll
    for (int q=0;q<16;q++)
      tmp[q] = (unsigned)f2bf(s[2*q][l]) | ((unsigned)f2bf(s[2*q+1][l])<<16);
    ui4* dst = (ui4*)(xt + ((size_t)b*NX + j)*32);
    #pragma unroll
    for (int q=0;q<4;q++){ ui4 v={tmp[4*q],tmp[4*q+1],tmp[4*q+2],tmp[4*q+3]}; dst[q]=v; }
  }
}

// ---- dilated k=2 conv as MFMA GEMM: o64-block, t64, 4 waves x t16.
// Weights K-half staged in LDS; output restaged -> full 128B-line writes.
template<int IC, int DIL, int NIN, int NOUT>
__global__ __launch_bounds__(256) void conv_g(
    const unsigned short* __restrict__ act,   // [8][NIN][IC]
    const unsigned short* __restrict__ wgt,   // [128][2*IC]
    const float* __restrict__ bias,           // [128]
    unsigned short* __restrict__ outp)        // [8][NOUT][128]
{
  constexpr int KT   = 2*IC;
  constexpr int NK   = KT/32;
  constexpr int NH   = (KT > 128) ? 2 : 1;
  constexpr int KPH  = KT / NH;
  constexpr int NKH  = KPH/32;
  constexpr int HRB  = KPH*2;
  constexpr int HCPR = HRB/16;
  __shared__ __align__(16) char wsm[64*HRB];
  __shared__ __align__(16) char outs[64*128];

  const int tid = threadIdx.x;
  const int b = blockIdx.z, ob = blockIdx.y, tb = blockIdx.x*64;
  const int o0g = ob*64;
  const int wid = tid>>6, l = tid&63, lo = l&15, hi = l>>4;

  bf16x8 bfr[NK];
  {
    const int tg = tb + wid*16 + lo;
    const int te = tg < NOUT ? tg : NOUT-1;
    #pragma unroll
    for (int kk=0;kk<NK;kk++){
      int k = kk*32 + hi*8;
      int tap = (k >= IC) ? 1 : 0;
      int off = k - tap*IC;
      bfr[kk] = *(const bf16x8*)(act + ((size_t)b*NIN + te + tap*DIL)*IC + off);
    }
  }

  f32x4 acc[4];
  #pragma unroll
  for (int m=0;m<4;m++) acc[m] = (f32x4){0.f,0.f,0.f,0.f};

  #pragma unroll
  for (int h=0; h<NH; ++h){
    __syncthreads();
    for (int c = tid; c < 64*HCPR; c += 256){
      int row = c / HCPR, cc = c % HCPR;
      ui4 v = *(const ui4*)((const char*)wgt + (size_t)(o0g+row)*KT*2 + h*HRB + cc*16);
      *(ui4*)(wsm + row*HRB + ((cc*16) ^ ((row&7)<<4))) = v;
    }
    __syncthreads();
    #pragma unroll
    for (int kk=0;kk<NKH;kk++){
      #pragma unroll
      for (int m=0;m<4;m++){
        int row = m*16 + lo;
        bf16x8 af = *(const bf16x8*)(wsm + row*HRB + ((kk*64+hi*16) ^ ((row&7)<<4)));
        acc[m] = __builtin_amdgcn_mfma_f32_16x16x32_bf16(af, bfr[h*NKH+kk], acc[m], 0,0,0);
      }
    }
  }
  __syncthreads();
  #pragma unroll
  for (int m=0;m<4;m++){
    const int ol = m*16 + hi*4;
    float b0v = bias[o0g+ol+0], b1v = bias[o0g+ol+1], b2v = bias[o0g+ol+2], b3v = bias[o0g+ol+3];
    int tl = wid*16 + lo;
    us4 v;
    v.x = f2bf(rrelu(acc[m][0] + b0v));
    v.y = f2bf(rrelu(acc[m][1] + b1v));
    v.z = f2bf(rrelu(acc[m][2] + b2v));
    v.w = f2bf(rrelu(acc[m][3] + b3v));
    *(us4*)(outs + tl*128 + ((ol*2) ^ ((tl&7)<<4))) = v;
  }
  __syncthreads();
  #pragma unroll
  for (int i=0;i<2;i++){
    int c = tid + i*256;
    int row = c>>3, cc = c&7;
    if (tb + row < NOUT){
      ui4 v = *(const ui4*)(outs + row*128 + ((cc*16) ^ ((row&7)<<4)));
      *(ui4*)(outp + ((size_t)b*NOUT + tb + row)*128 + o0g + cc*8) = v;
    }
  }
}

// ---- conv3(128->8,d=8) + rrelu + log-softmax + gumbel-softmax (fp32 math) ----
__global__ __launch_bounds__(64) void gumbel_g(
  const unsigned short* __restrict__ h2t,  // [8][N2][128] bf16
  const float* __restrict__ w3, const float* __restrict__ b3,
  const float* __restrict__ u,
  float* __restrict__ genz,                // [8][8][4096] fp32 (output 2)
  unsigned short* __restrict__ zt)         // [8][4096][32] bf16 (z padded to K=32)
{
  __shared__ unsigned hs[72][66];
  const int b = blockIdx.y, t0 = blockIdx.x*64, l = threadIdx.x;
  const unsigned* src = (const unsigned*)(h2t + ((size_t)b*N2 + t0)*128);
  for (int e=l; e<72*64; e+=64) hs[e>>6][e&63] = src[e];
  __syncthreads();

  float acc[8];
  #pragma unroll
  for (int r=0;r<8;r++) acc[r]=b3[r];
  for (int i2=0;i2<64;i2++){
    unsigned a0 = hs[l][i2], a1 = hs[l+8][i2];
    float v00 = bf2f(a0&0xffff), v01 = bf2f(a0>>16);
    float v10 = bf2f(a1&0xffff), v11 = bf2f(a1>>16);
    const int i = 2*i2;
    #pragma unroll
    for (int r=0;r<8;r++){
      acc[r] = fmaf(w3[(r*128+i)*2],     v00, acc[r]);
      acc[r] = fmaf(w3[(r*128+i)*2+1],   v10, acc[r]);
      acc[r] = fmaf(w3[(r*128+i+1)*2],   v01, acc[r]);
      acc[r] = fmaf(w3[(r*128+i+1)*2+1], v11, acc[r]);
    }
  }
  float m = -1e30f;
  #pragma unroll
  for (int r=0;r<8;r++){ acc[r] = rrelu(acc[r]); m = fmaxf(m, acc[r]); }
  float s = 0.f;
  #pragma unroll
  for (int r=0;r<8;r++) s += __expf(acc[r]-m);
  const float lse = m + __logf(s);
  const int t = t0 + l;
  const float* ub = u + ((size_t)b*4096 + t)*8;
  float y[8], m2 = -1e30f;
  #pragma unroll
  for (int r=0;r<8;r++){
    float g = -__logf(-__logf(ub[r]));
    y[r] = (acc[r] - lse + g)*10.f;
    m2 = fmaxf(m2, y[r]);
  }
  float s2 = 0.f;
  #pragma unroll
  for (int r=0;r<8;r++){ y[r] = __expf(y[r]-m2); s2 += y[r]; }
  const float inv = 1.f/s2;
  #pragma unroll
  for (int r=0;r<8;r++){
    y[r] *= inv;
    genz[((size_t)b*8+r)*4096 + t] = y[r];
  }
  ui4 zp = { (unsigned)f2bf(y[0]) | ((unsigned)f2bf(y[1])<<16),
             (unsigned)f2bf(y[2]) | ((unsigned)f2bf(y[3])<<16),
             (unsigned)f2bf(y[4]) | ((unsigned)f2bf(y[5])<<16),
             (unsigned)f2bf(y[6]) | ((unsigned)f2bf(y[7])<<16) };
  ui4 zz = {0,0,0,0};
  ui4* zd = (ui4*)(zt + ((size_t)b*4096 + t)*32);
  zd[0]=zp; zd[1]=zz; zd[2]=zz; zd[3]=zz;
}

// ---- FUSED MoE v3: 256 thr = 4 waves (avoids the 512-thr 128-VGPR cap).
// One block per (b,t64). Phase 1 (x2 o-halves): wave = o32(m2) x t64(n4),
// A global->reg, B from LDS; hid -> LDS (bf16 swizzled).
// Phase 2: wave = o16 x t64(n4), FULL K=256 (no k-split), A global->reg.
__global__ __launch_bounds__(256) void moe_f(
  const unsigned short* __restrict__ h2t,  // [8][N2][128]
  const float* __restrict__ genz,
  const unsigned short* __restrict__ zt,   // [8][4096][32]
  const unsigned short* __restrict__ pw0b, // [8][256][128]
  const unsigned short* __restrict__ pb0e, // [256][32]
  const unsigned short* __restrict__ pw1b, // [8][64][256]
  const unsigned short* __restrict__ pb1e, // [64][32]
  float* __restrict__ out)
{
  __shared__ __align__(16) char pres[16384];   // [t64][256B] swizzled
  __shared__ __align__(16) char hids[32768];   // [t64][512B] swizzled (hid bf16)
  __shared__ float zl[512];                    // [8][64]

  const int b = blockIdx.y, tb = blockIdx.x*64;
  const int tid = threadIdx.x;
  #pragma unroll
  for (int i=0;i<2;i++){
    int e = tid + i*256;
    zl[e] = genz[((size_t)b*8 + (e>>6))*4096 + tb + (e&63)];
  }
  {
    const char* src = (const char*)(h2t + ((size_t)b*N2 + tb + 8)*128);
    #pragma unroll
    for (int i=0;i<4;i++){
      int c = tid + i*256, row = c>>4, cc = c&15;
      ui4 v = *(const ui4*)(src + row*256 + cc*16);
      *(ui4*)(pres + row*256 + ((cc*16) ^ ((row&7)<<4))) = v;
    }
  }
  __syncthreads();

  const int wid = tid>>6, l = tid&63, lo = l&15, hi = l>>4;

  // ================= phase 1: hid = sum_r z_r (W0_r @ pre + b0_r) =========
  #pragma unroll
  for (int oh=0; oh<2; ++oh){
    const int ow = oh*128 + wid*32;            // wave's o32
    f32x4 acc[2][4];
    #pragma unroll
    for (int m=0;m<2;m++){
      bf16x8 pf = *(const bf16x8*)(pb0e + (size_t)(ow + m*16 + lo)*32 + hi*8);
      #pragma unroll
      for (int n=0;n<4;n++){
        bf16x8 zf = *(const bf16x8*)(zt + ((size_t)b*4096 + tb + n*16 + lo)*32 + hi*8);
        acc[m][n] = __builtin_amdgcn_mfma_f32_16x16x32_bf16(pf, zf, (f32x4){0.f,0.f,0.f,0.f}, 0,0,0);
      }
    }
    const unsigned short* abase0 = pw0b + (size_t)(ow + lo)*128 + hi*8;
    for (int r=0;r<8;r++){
      f32x4 ar[2][4];
      #pragma unroll
      for (int m=0;m<2;m++)
        #pragma unroll
        for (int n=0;n<4;n++) ar[m][n] = (f32x4){0.f,0.f,0.f,0.f};
      #pragma unroll
      for (int kk=0;kk<4;kk++){
        bf16x8 A0 = *(const bf16x8*)(abase0 + (size_t)r*32768 + kk*32);
        bf16x8 A1 = *(const bf16x8*)(abase0 + (size_t)r*32768 + 2048 + kk*32);
        #pragma unroll
        for (int n=0;n<4;n++){
          int tl = n*16 + lo;
          bf16x8 bf = *(const bf16x8*)(pres + tl*256 + ((kk*64 + hi*16) ^ ((tl&7)<<4)));
          ar[0][n] = __builtin_amdgcn_mfma_f32_16x16x32_bf16(A0, bf, ar[0][n], 0,0,0);
          ar[1][n] = __builtin_amdgcn_mfma_f32_16x16x32_bf16(A1, bf, ar[1][n], 0,0,0);
        }
      }
      #pragma unroll
      for (int n=0;n<4;n++){
        float zv = zl[r*64 + n*16 + lo];
        #pragma unroll
        for (int m=0;m<2;m++)
          #pragma unroll
          for (int c2=0;c2<4;c2++)
            acc[m][n][c2] = fmaf(zv, ar[m][n][c2], acc[m][n][c2]);
      }
    }
    // hid half -> LDS (each wave writes only its own o32 columns)
    #pragma unroll
    for (int m=0;m<2;m++){
      int ol2 = (ow + m*16 + hi*4)*2;
      #pragma unroll
      for (int n=0;n<4;n++){
        int tl = n*16 + lo;
        us4 v;
        v.x=f2bf(acc[m][n][0]); v.y=f2bf(acc[m][n][1]);
        v.z=f2bf(acc[m][n][2]); v.w=f2bf(acc[m][n][3]);
        *(us4*)(hids + tl*512 + (ol2 ^ ((tl&7)<<4))) = v;
      }
    }
  }
  __syncthreads();

  // ================= phase 2: out = transforms( sum_r z_r (W1_r @ hid + b1_r) )
  const int ow2 = wid*16;                      // 4 waves cover o64
  f32x4 acc2[4];
  {
    bf16x8 pf = *(const bf16x8*)(pb1e + (size_t)(ow2 + lo)*32 + hi*8);
    #pragma unroll
    for (int n=0;n<4;n++){
      bf16x8 zf = *(const bf16x8*)(zt + ((size_t)b*4096 + tb + n*16 + lo)*32 + hi*8);
      acc2[n] = __builtin_amdgcn_mfma_f32_16x16x32_bf16(pf, zf, (f32x4){0.f,0.f,0.f,0.f}, 0,0,0);
    }
  }
  const unsigned short* abase1 = pw1b + (size_t)(ow2 + lo)*256 + hi*8;
  for (int r=0;r<8;r++){
    f32x4 ar2[4];
    #pragma unroll
    for (int n=0;n<4;n++) ar2[n] = (f32x4){0.f,0.f,0.f,0.f};
    #pragma unroll
    for (int kk=0;kk<8;kk++){
      bf16x8 A2 = *(const bf16x8*)(abase1 + (size_t)r*16384 + kk*32);
      #pragma unroll
      for (int n=0;n<4;n++){
        int tl = n*16 + lo;
        bf16x8 bf = *(const bf16x8*)(hids + tl*512 + ((kk*64 + hi*16) ^ ((tl&7)<<4)));
        ar2[n] = __builtin_amdgcn_mfma_f32_16x16x32_bf16(A2, bf, ar2[n], 0,0,0);
      }
    }
    #pragma unroll
    for (int n=0;n<4;n++){
      float zv = zl[r*64 + n*16 + lo];
      #pragma unroll
      for (int c2=0;c2<4;c2++)
        acc2[n][c2] = fmaf(zv, ar2[n][c2], acc2[n][c2]);
    }
  }

  #pragma unroll
  for (int n=0;n<4;n++){
    int t = tb + n*16 + lo;
    #pragma unroll
    for (int c2=0;c2<4;c2++){
      int o = ow2 + hi*4 + c2;
      float v = acc2[n][c2];
      if (o < 32)
        out[((size_t)b*32 + o)*4096 + t] = v;
      else {
        float e = __expf(2.f*v);
        float th = 1.f - 2.f/(e+1.f);
        out[(size_t)1048576 + ((size_t)b*32 + (o-32))*4096 + t] = 0.5f + 0.5f*th + 0.001f;
      }
    }
  }
}

extern "C" void kernel_launch(void* const* d_in, const int* in_sizes, int n_in,
                              void* d_out, int out_size, void* d_ws, size_t ws_size,
                              hipStream_t stream) {
  const float* x   = (const float*)d_in[0];
  const float* u   = (const float*)d_in[1];
  const float* w0  = (const float*)d_in[2];
  const float* b0  = (const float*)d_in[3];
  const float* w1  = (const float*)d_in[4];
  const float* b1  = (const float*)d_in[5];
  const float* w2  = (const float*)d_in[6];
  const float* b2  = (const float*)d_in[7];
  const float* w3  = (const float*)d_in[8];
  const float* b3  = (const float*)d_in[9];
  const float* pw0 = (const float*)d_in[10];
  const float* pb0 = (const float*)d_in[11];
  const float* pw1 = (const float*)d_in[12];
  const float* pb1 = (const float*)d_in[13];

  float* out  = (float*)d_out;
  float* genz = out + (size_t)2*8*32*4096;

  char* p = (char*)d_ws;
  unsigned short* xt   = (unsigned short*)p; p += 2104832;   // 8*4111*32
  unsigned short* h0t  = (unsigned short*)p; p += 8417280;   // 8*4110*128
  unsigned short* h1t  = (unsigned short*)p; p += 8413184;   // 8*4108*128
  unsigned short* h2t  = (unsigned short*)p; p += 8404992;   // 8*4104*128
  unsigned short* ztb  = (unsigned short*)p; p += 2097152;   // 8*4096*32
  unsigned short* w0e  = (unsigned short*)p; p += 16384;
  unsigned short* w1e  = (unsigned short*)p; p += 65536;
  unsigned short* w2e  = (unsigned short*)p; p += 65536;
  unsigned short* pw0b = (unsigned short*)p; p += 524288;
  unsigned short* pw1b = (unsigned short*)p; p += 262144;
  unsigned short* pb0e = (unsigned short*)p; p += 16384;
  unsigned short* pb1e = (unsigned short*)p; p += 4096;

  prep_w<<<1864, 256, 0, stream>>>(w0,w1,w2,pw0,pw1,pb0,pb1,
                                   w0e,w1e,w2e,pw0b,pw1b,pb0e,pb1e);
  prep_xt<<<dim3(65,8), 64, 0, stream>>>(x, xt);
  conv_g<32,1,NX,N0><<<dim3(65,2,8), 256, 0, stream>>>(xt,  w0e, b0, h0t);
  conv_g<128,2,N0,N1><<<dim3(65,2,8), 256, 0, stream>>>(h0t, w1e, b1, h1t);
  conv_g<128,4,N1,N2><<<dim3(65,2,8), 256, 0, stream>>>(h1t, w2e, b2, h2t);
  gumbel_g<<<dim3(64,8), 64, 0, stream>>>(h2t, w3, b3, u, genz, ztb);
  moe_f<<<dim3(64,8), 256, 0, stream>>>(h2t, genz, ztb, pw0b, pb0e, pw1b, pb1e, out);
}

// Round 21
// 132.464 us; speedup vs baseline: 1.2208x; 1.0626x over previous
//
#include <hip/hip_runtime.h>
#include <math.h>

typedef __attribute__((ext_vector_type(8))) short bf16x8;   // 8 bf16 = 4 VGPR
typedef __attribute__((ext_vector_type(4))) float f32x4;    // MFMA acc
struct __align__(8)  us4 { unsigned short x,y,z,w; };
struct __align__(16) ui4 { unsigned x,y,z,w; };

#define SLOPE 0.2291666666666667f
constexpr int N0=4110, N1=4108, N2=4104, NX=4111;

__device__ __forceinline__ unsigned short f2bf(float f){
  unsigned u = __float_as_uint(f);
  u = (u + 0x7FFF + ((u>>16)&1)) >> 16;   // RNE
  return (unsigned short)u;
}
__device__ __forceinline__ float bf2f(unsigned short h){
  return __uint_as_float(((unsigned)h)<<16);
}
__device__ __forceinline__ float rrelu(float v){ return v>=0.f ? v : v*SLOPE; }

// ---- weight repack to bf16 (k = tap*IC + i for convs; bias panels [o][32]) ----
__global__ __launch_bounds__(256) void prep_w(
  const float* __restrict__ w0, const float* __restrict__ w1, const float* __restrict__ w2,
  const float* __restrict__ pw0, const float* __restrict__ pw1,
  const float* __restrict__ pb0, const float* __restrict__ pb1,
  unsigned short* __restrict__ w0e, unsigned short* __restrict__ w1e, unsigned short* __restrict__ w2e,
  unsigned short* __restrict__ pw0b, unsigned short* __restrict__ pw1b,
  unsigned short* __restrict__ pb0e, unsigned short* __restrict__ pb1e)
{
  int idx = blockIdx.x*256 + threadIdx.x;
  if (idx < 8192){ int oc=idx>>6, k=idx&63, tap=k>>5, i=k&31;
    w0e[idx] = f2bf(w0[(oc*32+i)*2+tap]); return; }
  idx -= 8192;
  if (idx < 32768){ int oc=idx>>8, k=idx&255, tap=k>>7, i=k&127;
    w1e[idx] = f2bf(w1[(oc*128+i)*2+tap]); return; }
  idx -= 32768;
  if (idx < 32768){ int oc=idx>>8, k=idx&255, tap=k>>7, i=k&127;
    w2e[idx] = f2bf(w2[(oc*128+i)*2+tap]); return; }
  idx -= 32768;
  if (idx < 262144){ pw0b[idx] = f2bf(pw0[idx]); return; }
  idx -= 262144;
  if (idx < 131072){ pw1b[idx] = f2bf(pw1[idx]); return; }
  idx -= 131072;
  if (idx < 8192){ int o=idx>>5, r=idx&31; pb0e[idx] = r<8 ? f2bf(pb0[r*256+o]) : (unsigned short)0; return; }
  idx -= 8192;
  if (idx < 2048){ int o=idx>>5, r=idx&31; pb1e[idx] = r<8 ? f2bf(pb1[r*64+o]) : (unsigned short)0; return; }
}

// ---- x (B,32,4096) fp32 -> xt (B,4111,32) bf16, 15 zero-pad rows in front ----
__global__ __launch_bounds__(64) void prep_xt(const float* __restrict__ x,
                                              unsigned short* __restrict__ xt)
{
  __shared__ float s[32][64];
  const int b = blockIdx.y, j0 = blockIdx.x*64, l = threadIdx.x;
  #pragma unroll 4
  for (int i=0;i<32;i++){
    int p = j0 + l - 15;
    s[i][l] = (p>=0 && p<4096) ? x[((size_t)b*32+i)*4096+p] : 0.f;
  }
  __syncthreads();
  const int j = j0 + l;
  if (j < NX){
    unsigned tmp[16];
    #pragma unroll
    for (int q=0;q<16;q++)
      tmp[q] = (unsigned)f2bf(s[2*q][l]) | ((unsigned)f2bf(s[2*q+1][l])<<16);
    ui4* dst = (ui4*)(xt + ((size_t)b*NX + j)*32);
    #pragma unroll
    for (int q=0;q<4;q++){ ui4 v={tmp[4*q],tmp[4*q+1],tmp[4*q+2],tmp[4*q+3]}; dst[q]=v; }
  }
}

// ---- dilated k=2 conv as MFMA GEMM: o64-block, t64, 4 waves x t16.
// Weights K-half staged in LDS; output restaged -> full 128B-line writes.
template<int IC, int DIL, int NIN, int NOUT>
__global__ __launch_bounds__(256) void conv_g(
    const unsigned short* __restrict__ act,   // [8][NIN][IC]
    const unsigned short* __restrict__ wgt,   // [128][2*IC]
    const float* __restrict__ bias,           // [128]
    unsigned short* __restrict__ outp)        // [8][NOUT][128]
{
  constexpr int KT   = 2*IC;
  constexpr int NK   = KT/32;
  constexpr int NH   = (KT > 128) ? 2 : 1;
  constexpr int KPH  = KT / NH;
  constexpr int NKH  = KPH/32;
  constexpr int HRB  = KPH*2;
  constexpr int HCPR = HRB/16;
  __shared__ __align__(16) char wsm[64*HRB];
  __shared__ __align__(16) char outs[64*128];

  const int tid = threadIdx.x;
  const int b = blockIdx.z, ob = blockIdx.y, tb = blockIdx.x*64;
  const int o0g = ob*64;
  const int wid = tid>>6, l = tid&63, lo = l&15, hi = l>>4;

  bf16x8 bfr[NK];
  {
    const int tg = tb + wid*16 + lo;
    const int te = tg < NOUT ? tg : NOUT-1;
    #pragma unroll
    for (int kk=0;kk<NK;kk++){
      int k = kk*32 + hi*8;
      int tap = (k >= IC) ? 1 : 0;
      int off = k - tap*IC;
      bfr[kk] = *(const bf16x8*)(act + ((size_t)b*NIN + te + tap*DIL)*IC + off);
    }
  }

  f32x4 acc[4];
  #pragma unroll
  for (int m=0;m<4;m++) acc[m] = (f32x4){0.f,0.f,0.f,0.f};

  #pragma unroll
  for (int h=0; h<NH; ++h){
    __syncthreads();
    for (int c = tid; c < 64*HCPR; c += 256){
      int row = c / HCPR, cc = c % HCPR;
      ui4 v = *(const ui4*)((const char*)wgt + (size_t)(o0g+row)*KT*2 + h*HRB + cc*16);
      *(ui4*)(wsm + row*HRB + ((cc*16) ^ ((row&7)<<4))) = v;
    }
    __syncthreads();
    #pragma unroll
    for (int kk=0;kk<NKH;kk++){
      #pragma unroll
      for (int m=0;m<4;m++){
        int row = m*16 + lo;
        bf16x8 af = *(const bf16x8*)(wsm + row*HRB + ((kk*64+hi*16) ^ ((row&7)<<4)));
        acc[m] = __builtin_amdgcn_mfma_f32_16x16x32_bf16(af, bfr[h*NKH+kk], acc[m], 0,0,0);
      }
    }
  }
  __syncthreads();
  #pragma unroll
  for (int m=0;m<4;m++){
    const int ol = m*16 + hi*4;
    float b0v = bias[o0g+ol+0], b1v = bias[o0g+ol+1], b2v = bias[o0g+ol+2], b3v = bias[o0g+ol+3];
    int tl = wid*16 + lo;
    us4 v;
    v.x = f2bf(rrelu(acc[m][0] + b0v));
    v.y = f2bf(rrelu(acc[m][1] + b1v));
    v.z = f2bf(rrelu(acc[m][2] + b2v));
    v.w = f2bf(rrelu(acc[m][3] + b3v));
    *(us4*)(outs + tl*128 + ((ol*2) ^ ((tl&7)<<4))) = v;
  }
  __syncthreads();
  #pragma unroll
  for (int i=0;i<2;i++){
    int c = tid + i*256;
    int row = c>>3, cc = c&7;
    if (tb + row < NOUT){
      ui4 v = *(const ui4*)(outs + row*128 + ((cc*16) ^ ((row&7)<<4)));
      *(ui4*)(outp + ((size_t)b*NOUT + tb + row)*128 + o0g + cc*8) = v;
    }
  }
}

// ---- conv3(128->8,d=8) + rrelu + log-softmax + gumbel-softmax (fp32 math) ----
__global__ __launch_bounds__(64) void gumbel_g(
  const unsigned short* __restrict__ h2t,  // [8][N2][128] bf16
  const float* __restrict__ w3, const float* __restrict__ b3,
  const float* __restrict__ u,
  float* __restrict__ genz,                // [8][8][4096] fp32 (output 2)
  unsigned short* __restrict__ zt)         // [8][4096][32] bf16 (z padded to K=32)
{
  __shared__ unsigned hs[72][66];
  const int b = blockIdx.y, t0 = blockIdx.x*64, l = threadIdx.x;
  const unsigned* src = (const unsigned*)(h2t + ((size_t)b*N2 + t0)*128);
  for (int e=l; e<72*64; e+=64) hs[e>>6][e&63] = src[e];
  __syncthreads();

  float acc[8];
  #pragma unroll
  for (int r=0;r<8;r++) acc[r]=b3[r];
  for (int i2=0;i2<64;i2++){
    unsigned a0 = hs[l][i2], a1 = hs[l+8][i2];
    float v00 = bf2f(a0&0xffff), v01 = bf2f(a0>>16);
    float v10 = bf2f(a1&0xffff), v11 = bf2f(a1>>16);
    const int i = 2*i2;
    #pragma unroll
    for (int r=0;r<8;r++){
      acc[r] = fmaf(w3[(r*128+i)*2],     v00, acc[r]);
      acc[r] = fmaf(w3[(r*128+i)*2+1],   v10, acc[r]);
      acc[r] = fmaf(w3[(r*128+i+1)*2],   v01, acc[r]);
      acc[r] = fmaf(w3[(r*128+i+1)*2+1], v11, acc[r]);
    }
  }
  float m = -1e30f;
  #pragma unroll
  for (int r=0;r<8;r++){ acc[r] = rrelu(acc[r]); m = fmaxf(m, acc[r]); }
  float s = 0.f;
  #pragma unroll
  for (int r=0;r<8;r++) s += __expf(acc[r]-m);
  const float lse = m + __logf(s);
  const int t = t0 + l;
  const float* ub = u + ((size_t)b*4096 + t)*8;
  float y[8], m2 = -1e30f;
  #pragma unroll
  for (int r=0;r<8;r++){
    float g = -__logf(-__logf(ub[r]));
    y[r] = (acc[r] - lse + g)*10.f;
    m2 = fmaxf(m2, y[r]);
  }
  float s2 = 0.f;
  #pragma unroll
  for (int r=0;r<8;r++){ y[r] = __expf(y[r]-m2); s2 += y[r]; }
  const float inv = 1.f/s2;
  #pragma unroll
  for (int r=0;r<8;r++){
    y[r] *= inv;
    genz[((size_t)b*8+r)*4096 + t] = y[r];
  }
  ui4 zp = { (unsigned)f2bf(y[0]) | ((unsigned)f2bf(y[1])<<16),
             (unsigned)f2bf(y[2]) | ((unsigned)f2bf(y[3])<<16),
             (unsigned)f2bf(y[4]) | ((unsigned)f2bf(y[5])<<16),
             (unsigned)f2bf(y[6]) | ((unsigned)f2bf(y[7])<<16) };
  ui4 zz = {0,0,0,0};
  ui4* zd = (ui4*)(zt + ((size_t)b*4096 + t)*32);
  zd[0]=zp; zd[1]=zz; zd[2]=zz; zd[3]=zz;
}

// ---- MoE layer 0 v10: wave-private A-streaming, ZERO r-loop barriers.
// Block 256 thr = 4 waves, tile o64 x t64; wave = o16(m1) x t64(n4).
// Each wave streams its OWN o16 A-frags global->reg (4 loads : 16 MFMAs per r,
// prefetched one r ahead, no LDS/no barriers). B pre-tile + z staged once.
// hidt blocked [8][4][4096][64]: per-block contiguous 8KB write.
__global__ __launch_bounds__(256) void moe1_m(
  const unsigned short* __restrict__ h2t,  // [8][N2][128]
  const float* __restrict__ genz,
  const unsigned short* __restrict__ zt,   // [8][4096][32]
  const unsigned short* __restrict__ pw0b, // [8][256][128]
  const unsigned short* __restrict__ pb0e, // [256][32]
  unsigned short* __restrict__ hidt)       // [8][4][4096][64]
{
  __shared__ __align__(16) char pres[16384];   // [t64][256B] swizzled
  __shared__ __align__(16) char outb[8192];    // [t64][o64 -> 128B] swizzled
  __shared__ float zl[512];                    // [8][64]

  const int ob = blockIdx.x, b = blockIdx.z, tb = blockIdx.y*64;
  const int o0g = ob*64;
  const int tid = threadIdx.x;
  #pragma unroll
  for (int i=0;i<2;i++){
    int e = tid + i*256;
    zl[e] = genz[((size_t)b*8 + (e>>6))*4096 + tb + (e&63)];
  }
  {
    const char* src = (const char*)(h2t + ((size_t)b*N2 + tb + 8)*128);
    #pragma unroll
    for (int i=0;i<4;i++){
      int c = tid + i*256, row = c>>4, cc = c&15;
      ui4 v = *(const ui4*)(src + row*256 + cc*16);
      *(ui4*)(pres + row*256 + ((cc*16) ^ ((row&7)<<4))) = v;
    }
  }
  __syncthreads();

  const int wid = tid>>6, l = tid&63, lo = l&15, hi = l>>4;
  const int ow = o0g + wid*16;                 // this wave's global o16 start

  // B fragments (t64 = n4, K128) from LDS pre-tile; z frags for bias MFMA
  bf16x8 bfr[4][4];
  #pragma unroll
  for (int n=0;n<4;n++){
    int tl = n*16 + lo;
    #pragma unroll
    for (int kk=0;kk<4;kk++)
      bfr[n][kk] = *(const bf16x8*)(pres + tl*256 + ((kk*64 + hi*16) ^ ((tl&7)<<4)));
  }
  f32x4 acc[4];
  {
    bf16x8 pf = *(const bf16x8*)(pb0e + (size_t)(ow + lo)*32 + hi*8);
    #pragma unroll
    for (int n=0;n<4;n++){
      bf16x8 zf = *(const bf16x8*)(zt + ((size_t)b*4096 + tb + n*16 + lo)*32 + hi*8);
      acc[n] = __builtin_amdgcn_mfma_f32_16x16x32_bf16(pf, zf, (f32x4){0.f,0.f,0.f,0.f}, 0,0,0);
    }
  }

  // A-frag streaming: lane addr base; frag(r,kk) at base + r*32768 + kk*32
  const unsigned short* abase = pw0b + (size_t)(ow + lo)*128 + hi*8;
  bf16x8 A[4], An[4];
  #pragma unroll
  for (int kk=0;kk<4;kk++) A[kk] = *(const bf16x8*)(abase + kk*32);

  #pragma unroll
  for (int r=0;r<8;r++){
    if (r < 7){
      #pragma unroll
      for (int kk=0;kk<4;kk++)
        An[kk] = *(const bf16x8*)(abase + (size_t)(r+1)*32768 + kk*32);
    }
    f32x4 ar[4];
    #pragma unroll
    for (int n=0;n<4;n++) ar[n] = (f32x4){0.f,0.f,0.f,0.f};
    #pragma unroll
    for (int kk=0;kk<4;kk++)
      #pragma unroll
      for (int n=0;n<4;n++)
        ar[n] = __builtin_amdgcn_mfma_f32_16x16x32_bf16(A[kk], bfr[n][kk], ar[n], 0,0,0);
    #pragma unroll
    for (int n=0;n<4;n++){
      float zv = zl[r*64 + n*16 + lo];
      #pragma unroll
      for (int c2=0;c2<4;c2++)
        acc[n][c2] = fmaf(zv, ar[n][c2], acc[n][c2]);
    }
    if (r < 7){
      #pragma unroll
      for (int kk=0;kk<4;kk++) A[kk] = An[kk];
    }
  }

  // epilogue: restage [t64][o64] swizzled (each wave fills its o16 columns),
  // then one contiguous 8KB write into this block's private hidt panel.
  #pragma unroll
  for (int n=0;n<4;n++){
    int tl = n*16 + lo;
    int ol2 = (wid*16 + hi*4)*2;
    us4 v;
    v.x=f2bf(acc[n][0]); v.y=f2bf(acc[n][1]); v.z=f2bf(acc[n][2]); v.w=f2bf(acc[n][3]);
    *(us4*)(outb + tl*128 + (ol2 ^ ((tl&7)<<4))) = v;
  }
  __syncthreads();
  #pragma unroll
  for (int i=0;i<2;i++){
    int c = tid + i*256, row = c>>3, cc = c&7;
    ui4 v = *(const ui4*)(outb + row*128 + ((cc*16) ^ ((row&7)<<4)));
    *(ui4*)(hidt + (((size_t)b*4 + ob)*4096 + tb + row)*64 + cc*8) = v;
  }
}

// ---- MoE layer 1: t128 block, 8 waves x t16, dbuf LDS weight panels.
// Linear decode; hidt reads remapped for blocked layout.
__global__ __launch_bounds__(512) void moe2_m(
  const unsigned short* __restrict__ hidt, // [8][4][4096][64]
  const float* __restrict__ genz,
  const unsigned short* __restrict__ zt,
  const unsigned short* __restrict__ pw1b, // [8][64][256]
  const unsigned short* __restrict__ pb1e, // [64][32]
  float* __restrict__ out)
{
  __shared__ __align__(16) char smem[32768*2 + 4096];
  char* abuf0 = smem;
  char* abuf1 = smem + 32768;
  float* zl  = (float*)(smem + 65536);     // [8][128]

  const int wg = blockIdx.x;
  const int b = wg >> 5, tb = (wg & 31) * 128;

  const int tid = threadIdx.x;
  #pragma unroll
  for (int i=0;i<2;i++){
    int e = tid + i*512;
    zl[e] = genz[((size_t)b*8 + (e>>7))*4096 + tb + (e&127)];
  }

  const int wid = tid>>6, l = tid&63, lo = l&15, hi = l>>4;
  const int tg = tb + wid*16 + lo;

  bf16x8 bfr[8];
  #pragma unroll
  for (int kk=0;kk<8;kk++)
    bfr[kk] = *(const bf16x8*)(hidt + (((size_t)b*4 + (kk>>1))*4096 + tg)*64 + (kk&1)*32 + hi*8);
  f32x4 acc[4];
  {
    bf16x8 zf = *(const bf16x8*)(zt + ((size_t)b*4096 + tg)*32 + hi*8);
    #pragma unroll
    for (int m=0;m<4;m++){
      bf16x8 pf = *(const bf16x8*)(pb1e + (size_t)(m*16 + lo)*32 + hi*8);
      acc[m] = __builtin_amdgcn_mfma_f32_16x16x32_bf16(pf, zf, (f32x4){0.f,0.f,0.f,0.f}, 0,0,0);
    }
  }

  {
    const char* src = (const char*)pw1b;
    #pragma unroll
    for (int i=0;i<4;i++){
      int c = tid + i*512, row = c>>5, cc = c&31;
      ui4 v = *(const ui4*)(src + row*512 + cc*16);
      *(ui4*)(abuf0 + row*512 + ((cc*16) ^ ((row&7)<<4))) = v;
    }
  }
  __syncthreads();

  #pragma unroll
  for (int r=0;r<8;r++){
    char* cur = (r&1) ? abuf1 : abuf0;
    char* nxt = (r&1) ? abuf0 : abuf1;
    ui4 stg[4];
    if (r < 7){
      const char* src = (const char*)(pw1b + (size_t)(r+1)*16384);
      #pragma unroll
      for (int i=0;i<4;i++){
        int c = tid + i*512;
        stg[i] = *(const ui4*)(src + (c>>5)*512 + (c&31)*16);
      }
    }
    f32x4 ar[4];
    #pragma unroll
    for (int m=0;m<4;m++) ar[m] = (f32x4){0.f,0.f,0.f,0.f};
    #pragma unroll
    for (int kk=0;kk<8;kk++){
      #pragma unroll
      for (int m=0;m<4;m++){
        int row = m*16 + lo;
        int kb  = kk*64 + hi*16;
        bf16x8 af = *(const bf16x8*)(cur + row*512 + (kb ^ ((row&7)<<4)));
        ar[m] = __builtin_amdgcn_mfma_f32_16x16x32_bf16(af, bfr[kk], ar[m], 0,0,0);
      }
    }
    float zv = zl[r*128 + wid*16 + lo];
    #pragma unroll
    for (int m=0;m<4;m++)
      #pragma unroll
      for (int c2=0;c2<4;c2++)
        acc[m][c2] = fmaf(zv, ar[m][c2], acc[m][c2]);
    if (r < 7){
      #pragma unroll
      for (int i=0;i<4;i++){
        int c = tid + i*512;
        *(ui4*)(nxt + (c>>5)*512 + (((c&31)*16) ^ (((c>>5)&7)<<4))) = stg[i];
      }
    }
    __syncthreads();
  }

  #pragma unroll
  for (int m=0;m<4;m++){
    #pragma unroll
    for (int c2=0;c2<4;c2++){
      int o = m*16 + hi*4 + c2;
      float v = acc[m][c2];
      if (o < 32)
        out[((size_t)b*32 + o)*4096 + tg] = v;
      else {
        float e = __expf(2.f*v);
        float th = 1.f - 2.f/(e+1.f);
        out[(size_t)1048576 + ((size_t)b*32 + (o-32))*4096 + tg] = 0.5f + 0.5f*th + 0.001f;
      }
    }
  }
}

extern "C" void kernel_launch(void* const* d_in, const int* in_sizes, int n_in,
                              void* d_out, int out_size, void* d_ws, size_t ws_size,
                              hipStream_t stream) {
  const float* x   = (const float*)d_in[0];
  const float* u   = (const float*)d_in[1];
  const float* w0  = (const float*)d_in[2];
  const float* b0  = (const float*)d_in[3];
  const float* w1  = (const float*)d_in[4];
  const float* b1  = (const float*)d_in[5];
  const float* w2  = (const float*)d_in[6];
  const float* b2  = (const float*)d_in[7];
  const float* w3  = (const float*)d_in[8];
  const float* b3  = (const float*)d_in[9];
  const float* pw0 = (const float*)d_in[10];
  const float* pb0 = (const float*)d_in[11];
  const float* pw1 = (const float*)d_in[12];
  const float* pb1 = (const float*)d_in[13];

  float* out  = (float*)d_out;
  float* genz = out + (size_t)2*8*32*4096;

  char* p = (char*)d_ws;
  unsigned short* xt   = (unsigned short*)p; p += 2104832;   // 8*4111*32
  unsigned short* h0t  = (unsigned short*)p; p += 8417280;   // 8*4110*128
  unsigned short* h1t  = (unsigned short*)p; p += 8413184;   // 8*4108*128
  unsigned short* h2t  = (unsigned short*)p; p += 8404992;   // 8*4104*128
  unsigned short* ztb  = (unsigned short*)p; p += 2097152;   // 8*4096*32
  unsigned short* hidt = (unsigned short*)p; p += 16777216;  // 8*4*4096*64 (blocked)
  unsigned short* w0e  = (unsigned short*)p; p += 16384;
  unsigned short* w1e  = (unsigned short*)p; p += 65536;
  unsigned short* w2e  = (unsigned short*)p; p += 65536;
  unsigned short* pw0b = (unsigned short*)p; p += 524288;
  unsigned short* pw1b = (unsigned short*)p; p += 262144;
  unsigned short* pb0e = (unsigned short*)p; p += 16384;
  unsigned short* pb1e = (unsigned short*)p; p += 4096;

  prep_w<<<1864, 256, 0, stream>>>(w0,w1,w2,pw0,pw1,pb0,pb1,
                                   w0e,w1e,w2e,pw0b,pw1b,pb0e,pb1e);
  prep_xt<<<dim3(65,8), 64, 0, stream>>>(x, xt);
  conv_g<32,1,NX,N0><<<dim3(65,2,8), 256, 0, stream>>>(xt,  w0e, b0, h0t);
  conv_g<128,2,N0,N1><<<dim3(65,2,8), 256, 0, stream>>>(h0t, w1e, b1, h1t);
  conv_g<128,4,N1,N2><<<dim3(65,2,8), 256, 0, stream>>>(h1t, w2e, b2, h2t);
  gumbel_g<<<dim3(64,8), 64, 0, stream>>>(h2t, w3, b3, u, genz, ztb);
  moe1_m<<<dim3(4,64,8), 256, 0, stream>>>(h2t, genz, ztb, pw0b, pb0e, hidt);
  moe2_m<<<256, 512, 0, stream>>>(hidt, genz, ztb, pw1b, pb1e, out);
}

// Round 22
// 127.704 us; speedup vs baseline: 1.2663x; 1.0373x over previous
//
#include <hip/hip_runtime.h>
#include <math.h>

typedef __attribute__((ext_vector_type(8))) short bf16x8;   // 8 bf16 = 4 VGPR
typedef __attribute__((ext_vector_type(4))) float f32x4;    // MFMA acc
struct __align__(8)  us4 { unsigned short x,y,z,w; };
struct __align__(16) ui4 { unsigned x,y,z,w; };

#define SLOPE 0.2291666666666667f
constexpr int N0=4110, N1=4108, N2=4104, NX=4111;

__device__ __forceinline__ unsigned short f2bf(float f){
  unsigned u = __float_as_uint(f);
  u = (u + 0x7FFF + ((u>>16)&1)) >> 16;   // RNE
  return (unsigned short)u;
}
__device__ __forceinline__ float bf2f(unsigned short h){
  return __uint_as_float(((unsigned)h)<<16);
}
__device__ __forceinline__ float rrelu(float v){ return v>=0.f ? v : v*SLOPE; }

// ---- weight repack to bf16 (k = tap*IC + i for convs; bias panels [o][32]) ----
__global__ __launch_bounds__(256) void prep_w(
  const float* __restrict__ w0, const float* __restrict__ w1, const float* __restrict__ w2,
  const float* __restrict__ pw0, const float* __restrict__ pw1,
  const float* __restrict__ pb0, const float* __restrict__ pb1,
  unsigned short* __restrict__ w0e, unsigned short* __restrict__ w1e, unsigned short* __restrict__ w2e,
  unsigned short* __restrict__ pw0b, unsigned short* __restrict__ pw1b,
  unsigned short* __restrict__ pb0e, unsigned short* __restrict__ pb1e)
{
  int idx = blockIdx.x*256 + threadIdx.x;
  if (idx < 8192){ int oc=idx>>6, k=idx&63, tap=k>>5, i=k&31;
    w0e[idx] = f2bf(w0[(oc*32+i)*2+tap]); return; }
  idx -= 8192;
  if (idx < 32768){ int oc=idx>>8, k=idx&255, tap=k>>7, i=k&127;
    w1e[idx] = f2bf(w1[(oc*128+i)*2+tap]); return; }
  idx -= 32768;
  if (idx < 32768){ int oc=idx>>8, k=idx&255, tap=k>>7, i=k&127;
    w2e[idx] = f2bf(w2[(oc*128+i)*2+tap]); return; }
  idx -= 32768;
  if (idx < 262144){ pw0b[idx] = f2bf(pw0[idx]); return; }
  idx -= 262144;
  if (idx < 131072){ pw1b[idx] = f2bf(pw1[idx]); return; }
  idx -= 131072;
  if (idx < 8192){ int o=idx>>5, r=idx&31; pb0e[idx] = r<8 ? f2bf(pb0[r*256+o]) : (unsigned short)0; return; }
  idx -= 8192;
  if (idx < 2048){ int o=idx>>5, r=idx&31; pb1e[idx] = r<8 ? f2bf(pb1[r*64+o]) : (unsigned short)0; return; }
}

// ---- x (B,32,4096) fp32 -> xt (B,4111,32) bf16, 15 zero-pad rows in front ----
__global__ __launch_bounds__(64) void prep_xt(const float* __restrict__ x,
                                              unsigned short* __restrict__ xt)
{
  __shared__ float s[32][64];
  const int b = blockIdx.y, j0 = blockIdx.x*64, l = threadIdx.x;
  #pragma unroll 4
  for (int i=0;i<32;i++){
    int p = j0 + l - 15;
    s[i][l] = (p>=0 && p<4096) ? x[((size_t)b*32+i)*4096+p] : 0.f;
  }
  __syncthreads();
  const int j = j0 + l;
  if (j < NX){
    unsigned tmp[16];
    #pragma unroll
    for (int q=0;q<16;q++)
      tmp[q] = (unsigned)f2bf(s[2*q][l]) | ((unsigned)f2bf(s[2*q+1][l])<<16);
    ui4* dst = (ui4*)(xt + ((size_t)b*NX + j)*32);
    #pragma unroll
    for (int q=0;q<4;q++){ ui4 v={tmp[4*q],tmp[4*q+1],tmp[4*q+2],tmp[4*q+3]}; dst[q]=v; }
  }
}

// ---- dilated k=2 conv as MFMA GEMM: o64-block, t64, 4 waves x t16.
// Weights K-half staged in LDS; output restaged -> full 128B-line writes.
template<int IC, int DIL, int NIN, int NOUT>
__global__ __launch_bounds__(256) void conv_g(
    const unsigned short* __restrict__ act,   // [8][NIN][IC]
    const unsigned short* __restrict__ wgt,   // [128][2*IC]
    const float* __restrict__ bias,           // [128]
    unsigned short* __restrict__ outp)        // [8][NOUT][128]
{
  constexpr int KT   = 2*IC;
  constexpr int NK   = KT/32;
  constexpr int NH   = (KT > 128) ? 2 : 1;
  constexpr int KPH  = KT / NH;
  constexpr int NKH  = KPH/32;
  constexpr int HRB  = KPH*2;
  constexpr int HCPR = HRB/16;
  __shared__ __align__(16) char wsm[64*HRB];
  __shared__ __align__(16) char outs[64*128];

  const int tid = threadIdx.x;
  const int b = blockIdx.z, ob = blockIdx.y, tb = blockIdx.x*64;
  const int o0g = ob*64;
  const int wid = tid>>6, l = tid&63, lo = l&15, hi = l>>4;

  bf16x8 bfr[NK];
  {
    const int tg = tb + wid*16 + lo;
    const int te = tg < NOUT ? tg : NOUT-1;
    #pragma unroll
    for (int kk=0;kk<NK;kk++){
      int k = kk*32 + hi*8;
      int tap = (k >= IC) ? 1 : 0;
      int off = k - tap*IC;
      bfr[kk] = *(const bf16x8*)(act + ((size_t)b*NIN + te + tap*DIL)*IC + off);
    }
  }

  f32x4 acc[4];
  #pragma unroll
  for (int m=0;m<4;m++) acc[m] = (f32x4){0.f,0.f,0.f,0.f};

  #pragma unroll
  for (int h=0; h<NH; ++h){
    __syncthreads();
    for (int c = tid; c < 64*HCPR; c += 256){
      int row = c / HCPR, cc = c % HCPR;
      ui4 v = *(const ui4*)((const char*)wgt + (size_t)(o0g+row)*KT*2 + h*HRB + cc*16);
      *(ui4*)(wsm + row*HRB + ((cc*16) ^ ((row&7)<<4))) = v;
    }
    __syncthreads();
    #pragma unroll
    for (int kk=0;kk<NKH;kk++){
      #pragma unroll
      for (int m=0;m<4;m++){
        int row = m*16 + lo;
        bf16x8 af = *(const bf16x8*)(wsm + row*HRB + ((kk*64+hi*16) ^ ((row&7)<<4)));
        acc[m] = __builtin_amdgcn_mfma_f32_16x16x32_bf16(af, bfr[h*NKH+kk], acc[m], 0,0,0);
      }
    }
  }
  __syncthreads();
  #pragma unroll
  for (int m=0;m<4;m++){
    const int ol = m*16 + hi*4;
    float b0v = bias[o0g+ol+0], b1v = bias[o0g+ol+1], b2v = bias[o0g+ol+2], b3v = bias[o0g+ol+3];
    int tl = wid*16 + lo;
    us4 v;
    v.x = f2bf(rrelu(acc[m][0] + b0v));
    v.y = f2bf(rrelu(acc[m][1] + b1v));
    v.z = f2bf(rrelu(acc[m][2] + b2v));
    v.w = f2bf(rrelu(acc[m][3] + b3v));
    *(us4*)(outs + tl*128 + ((ol*2) ^ ((tl&7)<<4))) = v;
  }
  __syncthreads();
  #pragma unroll
  for (int i=0;i<2;i++){
    int c = tid + i*256;
    int row = c>>3, cc = c&7;
    if (tb + row < NOUT){
      ui4 v = *(const ui4*)(outs + row*128 + ((cc*16) ^ ((row&7)<<4)));
      *(ui4*)(outp + ((size_t)b*NOUT + tb + row)*128 + o0g + cc*8) = v;
    }
  }
}

// ---- conv3(128->8,d=8) + rrelu + log-softmax + gumbel-softmax (fp32 math) ----
__global__ __launch_bounds__(64) void gumbel_g(
  const unsigned short* __restrict__ h2t,  // [8][N2][128] bf16
  const float* __restrict__ w3, const float* __restrict__ b3,
  const float* __restrict__ u,
  float* __restrict__ genz,                // [8][8][4096] fp32 (output 2)
  unsigned short* __restrict__ zt)         // [8][4096][32] bf16 (z padded to K=32)
{
  __shared__ unsigned hs[72][66];
  const int b = blockIdx.y, t0 = blockIdx.x*64, l = threadIdx.x;
  const unsigned* src = (const unsigned*)(h2t + ((size_t)b*N2 + t0)*128);
  for (int e=l; e<72*64; e+=64) hs[e>>6][e&63] = src[e];
  __syncthreads();

  float acc[8];
  #pragma unroll
  for (int r=0;r<8;r++) acc[r]=b3[r];
  for (int i2=0;i2<64;i2++){
    unsigned a0 = hs[l][i2], a1 = hs[l+8][i2];
    float v00 = bf2f(a0&0xffff), v01 = bf2f(a0>>16);
    float v10 = bf2f(a1&0xffff), v11 = bf2f(a1>>16);
    const int i = 2*i2;
    #pragma unroll
    for (int r=0;r<8;r++){
      acc[r] = fmaf(w3[(r*128+i)*2],     v00, acc[r]);
      acc[r] = fmaf(w3[(r*128+i)*2+1],   v10, acc[r]);
      acc[r] = fmaf(w3[(r*128+i+1)*2],   v01, acc[r]);
      acc[r] = fmaf(w3[(r*128+i+1)*2+1], v11, acc[r]);
    }
  }
  float m = -1e30f;
  #pragma unroll
  for (int r=0;r<8;r++){ acc[r] = rrelu(acc[r]); m = fmaxf(m, acc[r]); }
  float s = 0.f;
  #pragma unroll
  for (int r=0;r<8;r++) s += __expf(acc[r]-m);
  const float lse = m + __logf(s);
  const int t = t0 + l;
  const float* ub = u + ((size_t)b*4096 + t)*8;
  float y[8], m2 = -1e30f;
  #pragma unroll
  for (int r=0;r<8;r++){
    float g = -__logf(-__logf(ub[r]));
    y[r] = (acc[r] - lse + g)*10.f;
    m2 = fmaxf(m2, y[r]);
  }
  float s2 = 0.f;
  #pragma unroll
  for (int r=0;r<8;r++){ y[r] = __expf(y[r]-m2); s2 += y[r]; }
  const float inv = 1.f/s2;
  #pragma unroll
  for (int r=0;r<8;r++){
    y[r] *= inv;
    genz[((size_t)b*8+r)*4096 + t] = y[r];
  }
  ui4 zp = { (unsigned)f2bf(y[0]) | ((unsigned)f2bf(y[1])<<16),
             (unsigned)f2bf(y[2]) | ((unsigned)f2bf(y[3])<<16),
             (unsigned)f2bf(y[4]) | ((unsigned)f2bf(y[5])<<16),
             (unsigned)f2bf(y[6]) | ((unsigned)f2bf(y[7])<<16) };
  ui4 zz = {0,0,0,0};
  ui4* zd = (ui4*)(zt + ((size_t)b*4096 + t)*32);
  zd[0]=zp; zd[1]=zz; zd[2]=zz; zd[3]=zz;
}

// ---- MoE layer 0 v14: o64 x t128 block (1024 blocks -- half the per-block
// latency taxes of v10). 4 waves = 4 o16; wave = o16(m1) x t128(n8).
// B read from LDS pre-tile inside the r-loop (no register B array);
// A wave-private streamed global->reg with 1-r prefetch; zero r-loop barriers.
// hidt blocked [8][4][4096][64]: per-block contiguous 16KB write.
__global__ __launch_bounds__(256) void moe1_m(
  const unsigned short* __restrict__ h2t,  // [8][N2][128]
  const float* __restrict__ genz,
  const unsigned short* __restrict__ zt,   // [8][4096][32]
  const unsigned short* __restrict__ pw0b, // [8][256][128]
  const unsigned short* __restrict__ pb0e, // [256][32]
  unsigned short* __restrict__ hidt)       // [8][4][4096][64]
{
  __shared__ __align__(16) char pres[32768];   // [t128][256B] swizzled
  __shared__ __align__(16) char outb[16384];   // [t128][o64 -> 128B] swizzled
  __shared__ float zl[1024];                   // [8][128]

  const int ob = blockIdx.x, b = blockIdx.z, tb = blockIdx.y*128;
  const int o0g = ob*64;
  const int tid = threadIdx.x;
  #pragma unroll
  for (int i=0;i<4;i++){
    int e = tid + i*256;
    zl[e] = genz[((size_t)b*8 + (e>>7))*4096 + tb + (e&127)];
  }
  {
    const char* src = (const char*)(h2t + ((size_t)b*N2 + tb + 8)*128);
    #pragma unroll
    for (int i=0;i<8;i++){
      int c = tid + i*256, row = c>>4, cc = c&15;
      ui4 v = *(const ui4*)(src + row*256 + cc*16);
      *(ui4*)(pres + row*256 + ((cc*16) ^ ((row&7)<<4))) = v;
    }
  }
  __syncthreads();

  const int wid = tid>>6, l = tid&63, lo = l&15, hi = l>>4;
  const int ow = o0g + wid*16;                 // this wave's global o16 start

  f32x4 acc[8];
  {
    bf16x8 pf = *(const bf16x8*)(pb0e + (size_t)(ow + lo)*32 + hi*8);
    #pragma unroll
    for (int n=0;n<8;n++){
      bf16x8 zf = *(const bf16x8*)(zt + ((size_t)b*4096 + tb + n*16 + lo)*32 + hi*8);
      acc[n] = __builtin_amdgcn_mfma_f32_16x16x32_bf16(pf, zf, (f32x4){0.f,0.f,0.f,0.f}, 0,0,0);
    }
  }

  // A-frag streaming: frag(r,kk) at base + r*32768 + kk*32
  const unsigned short* abase = pw0b + (size_t)(ow + lo)*128 + hi*8;
  bf16x8 A[4], An[4];
  #pragma unroll
  for (int kk=0;kk<4;kk++) A[kk] = *(const bf16x8*)(abase + kk*32);

  #pragma unroll
  for (int r=0;r<8;r++){
    if (r < 7){
      #pragma unroll
      for (int kk=0;kk<4;kk++)
        An[kk] = *(const bf16x8*)(abase + (size_t)(r+1)*32768 + kk*32);
    }
    f32x4 ar[8];
    #pragma unroll
    for (int n=0;n<8;n++) ar[n] = (f32x4){0.f,0.f,0.f,0.f};
    #pragma unroll
    for (int kk=0;kk<4;kk++){
      #pragma unroll
      for (int n=0;n<8;n++){
        int tl = n*16 + lo;
        bf16x8 bf = *(const bf16x8*)(pres + tl*256 + ((kk*64 + hi*16) ^ ((tl&7)<<4)));
        ar[n] = __builtin_amdgcn_mfma_f32_16x16x32_bf16(A[kk], bf, ar[n], 0,0,0);
      }
    }
    #pragma unroll
    for (int n=0;n<8;n++){
      float zv = zl[r*128 + n*16 + lo];
      #pragma unroll
      for (int c2=0;c2<4;c2++)
        acc[n][c2] = fmaf(zv, ar[n][c2], acc[n][c2]);
    }
    if (r < 7){
      #pragma unroll
      for (int kk=0;kk<4;kk++) A[kk] = An[kk];
    }
  }

  // epilogue: restage [t128][o64] swizzled, then contiguous 16KB hidt write
  #pragma unroll
  for (int n=0;n<8;n++){
    int tl = n*16 + lo;
    int ol2 = (wid*16 + hi*4)*2;
    us4 v;
    v.x=f2bf(acc[n][0]); v.y=f2bf(acc[n][1]); v.z=f2bf(acc[n][2]); v.w=f2bf(acc[n][3]);
    *(us4*)(outb + tl*128 + (ol2 ^ ((tl&7)<<4))) = v;
  }
  __syncthreads();
  #pragma unroll
  for (int i=0;i<4;i++){
    int c = tid + i*256, row = c>>3, cc = c&7;
    ui4 v = *(const ui4*)(outb + row*128 + ((cc*16) ^ ((row&7)<<4)));
    *(ui4*)(hidt + (((size_t)b*4 + ob)*4096 + tb + row)*64 + cc*8) = v;
  }
}

// ---- MoE layer 1: t128 block, 8 waves x t16, dbuf LDS weight panels.
// Linear decode; hidt reads remapped for blocked layout.
__global__ __launch_bounds__(512) void moe2_m(
  const unsigned short* __restrict__ hidt, // [8][4][4096][64]
  const float* __restrict__ genz,
  const unsigned short* __restrict__ zt,
  const unsigned short* __restrict__ pw1b, // [8][64][256]
  const unsigned short* __restrict__ pb1e, // [64][32]
  float* __restrict__ out)
{
  __shared__ __align__(16) char smem[32768*2 + 4096];
  char* abuf0 = smem;
  char* abuf1 = smem + 32768;
  float* zl  = (float*)(smem + 65536);     // [8][128]

  const int wg = blockIdx.x;
  const int b = wg >> 5, tb = (wg & 31) * 128;

  const int tid = threadIdx.x;
  #pragma unroll
  for (int i=0;i<2;i++){
    int e = tid + i*512;
    zl[e] = genz[((size_t)b*8 + (e>>7))*4096 + tb + (e&127)];
  }

  const int wid = tid>>6, l = tid&63, lo = l&15, hi = l>>4;
  const int tg = tb + wid*16 + lo;

  bf16x8 bfr[8];
  #pragma unroll
  for (int kk=0;kk<8;kk++)
    bfr[kk] = *(const bf16x8*)(hidt + (((size_t)b*4 + (kk>>1))*4096 + tg)*64 + (kk&1)*32 + hi*8);
  f32x4 acc[4];
  {
    bf16x8 zf = *(const bf16x8*)(zt + ((size_t)b*4096 + tg)*32 + hi*8);
    #pragma unroll
    for (int m=0;m<4;m++){
      bf16x8 pf = *(const bf16x8*)(pb1e + (size_t)(m*16 + lo)*32 + hi*8);
      acc[m] = __builtin_amdgcn_mfma_f32_16x16x32_bf16(pf, zf, (f32x4){0.f,0.f,0.f,0.f}, 0,0,0);
    }
  }

  {
    const char* src = (const char*)pw1b;
    #pragma unroll
    for (int i=0;i<4;i++){
      int c = tid + i*512, row = c>>5, cc = c&31;
      ui4 v = *(const ui4*)(src + row*512 + cc*16);
      *(ui4*)(abuf0 + row*512 + ((cc*16) ^ ((row&7)<<4))) = v;
    }
  }
  __syncthreads();

  #pragma unroll
  for (int r=0;r<8;r++){
    char* cur = (r&1) ? abuf1 : abuf0;
    char* nxt = (r&1) ? abuf0 : abuf1;
    ui4 stg[4];
    if (r < 7){
      const char* src = (const char*)(pw1b + (size_t)(r+1)*16384);
      #pragma unroll
      for (int i=0;i<4;i++){
        int c = tid + i*512;
        stg[i] = *(const ui4*)(src + (c>>5)*512 + (c&31)*16);
      }
    }
    f32x4 ar[4];
    #pragma unroll
    for (int m=0;m<4;m++) ar[m] = (f32x4){0.f,0.f,0.f,0.f};
    #pragma unroll
    for (int kk=0;kk<8;kk++){
      #pragma unroll
      for (int m=0;m<4;m++){
        int row = m*16 + lo;
        int kb  = kk*64 + hi*16;
        bf16x8 af = *(const bf16x8*)(cur + row*512 + (kb ^ ((row&7)<<4)));
        ar[m] = __builtin_amdgcn_mfma_f32_16x16x32_bf16(af, bfr[kk], ar[m], 0,0,0);
      }
    }
    float zv = zl[r*128 + wid*16 + lo];
    #pragma unroll
    for (int m=0;m<4;m++)
      #pragma unroll
      for (int c2=0;c2<4;c2++)
        acc[m][c2] = fmaf(zv, ar[m][c2], acc[m][c2]);
    if (r < 7){
      #pragma unroll
      for (int i=0;i<4;i++){
        int c = tid + i*512;
        *(ui4*)(nxt + (c>>5)*512 + (((c&31)*16) ^ (((c>>5)&7)<<4))) = stg[i];
      }
    }
    __syncthreads();
  }

  #pragma unroll
  for (int m=0;m<4;m++){
    #pragma unroll
    for (int c2=0;c2<4;c2++){
      int o = m*16 + hi*4 + c2;
      float v = acc[m][c2];
      if (o < 32)
        out[((size_t)b*32 + o)*4096 + tg] = v;
      else {
        float e = __expf(2.f*v);
        float th = 1.f - 2.f/(e+1.f);
        out[(size_t)1048576 + ((size_t)b*32 + (o-32))*4096 + tg] = 0.5f + 0.5f*th + 0.001f;
      }
    }
  }
}

extern "C" void kernel_launch(void* const* d_in, const int* in_sizes, int n_in,
                              void* d_out, int out_size, void* d_ws, size_t ws_size,
                              hipStream_t stream) {
  const float* x   = (const float*)d_in[0];
  const float* u   = (const float*)d_in[1];
  const float* w0  = (const float*)d_in[2];
  const float* b0  = (const float*)d_in[3];
  const float* w1  = (const float*)d_in[4];
  const float* b1  = (const float*)d_in[5];
  const float* w2  = (const float*)d_in[6];
  const float* b2  = (const float*)d_in[7];
  const float* w3  = (const float*)d_in[8];
  const float* b3  = (const float*)d_in[9];
  const float* pw0 = (const float*)d_in[10];
  const float* pb0 = (const float*)d_in[11];
  const float* pw1 = (const float*)d_in[12];
  const float* pb1 = (const float*)d_in[13];

  float* out  = (float*)d_out;
  float* genz = out + (size_t)2*8*32*4096;

  char* p = (char*)d_ws;
  unsigned short* xt   = (unsigned short*)p; p += 2104832;   // 8*4111*32
  unsigned short* h0t  = (unsigned short*)p; p += 8417280;   // 8*4110*128
  unsigned short* h1t  = (unsigned short*)p; p += 8413184;   // 8*4108*128
  unsigned short* h2t  = (unsigned short*)p; p += 8404992;   // 8*4104*128
  unsigned short* ztb  = (unsigned short*)p; p += 2097152;   // 8*4096*32
  unsigned short* hidt = (unsigned short*)p; p += 16777216;  // 8*4*4096*64 (blocked)
  unsigned short* w0e  = (unsigned short*)p; p += 16384;
  unsigned short* w1e  = (unsigned short*)p; p += 65536;
  unsigned short* w2e  = (unsigned short*)p; p += 65536;
  unsigned short* pw0b = (unsigned short*)p; p += 524288;
  unsigned short* pw1b = (unsigned short*)p; p += 262144;
  unsigned short* pb0e = (unsigned short*)p; p += 16384;
  unsigned short* pb1e = (unsigned short*)p; p += 4096;

  prep_w<<<1864, 256, 0, stream>>>(w0,w1,w2,pw0,pw1,pb0,pb1,
                                   w0e,w1e,w2e,pw0b,pw1b,pb0e,pb1e);
  prep_xt<<<dim3(65,8), 64, 0, stream>>>(x, xt);
  conv_g<32,1,NX,N0><<<dim3(65,2,8), 256, 0, stream>>>(xt,  w0e, b0, h0t);
  conv_g<128,2,N0,N1><<<dim3(65,2,8), 256, 0, stream>>>(h0t, w1e, b1, h1t);
  conv_g<128,4,N1,N2><<<dim3(65,2,8), 256, 0, stream>>>(h1t, w2e, b2, h2t);
  gumbel_g<<<dim3(64,8), 64, 0, stream>>>(h2t, w3, b3, u, genz, ztb);
  moe1_m<<<dim3(4,32,8), 256, 0, stream>>>(h2t, genz, ztb, pw0b, pb0e, hidt);
  moe2_m<<<256, 512, 0, stream>>>(hidt, genz, ztb, pw1b, pb1e, out);
}

// Round 23
// 127.565 us; speedup vs baseline: 1.2676x; 1.0011x over previous
//
#include <hip/hip_runtime.h>
#include <math.h>

typedef __attribute__((ext_vector_type(8))) short bf16x8;   // 8 bf16 = 4 VGPR
typedef __attribute__((ext_vector_type(4))) float f32x4;    // MFMA acc
struct __align__(8)  us4 { unsigned short x,y,z,w; };
struct __align__(16) ui4 { unsigned x,y,z,w; };

#define SLOPE 0.2291666666666667f
constexpr int N0=4110, N1=4108, N2=4104, NX=4111;

__device__ __forceinline__ unsigned short f2bf(float f){
  unsigned u = __float_as_uint(f);
  u = (u + 0x7FFF + ((u>>16)&1)) >> 16;   // RNE
  return (unsigned short)u;
}
__device__ __forceinline__ float bf2f(unsigned short h){
  return __uint_as_float(((unsigned)h)<<16);
}
__device__ __forceinline__ float rrelu(float v){ return v>=0.f ? v : v*SLOPE; }

// ---- weight repack to bf16 (k = tap*IC + i for convs; bias panels [o][32]) ----
__global__ __launch_bounds__(256) void prep_w(
  const float* __restrict__ w0, const float* __restrict__ w1, const float* __restrict__ w2,
  const float* __restrict__ pw0, const float* __restrict__ pw1,
  const float* __restrict__ pb0, const float* __restrict__ pb1,
  unsigned short* __restrict__ w0e, unsigned short* __restrict__ w1e, unsigned short* __restrict__ w2e,
  unsigned short* __restrict__ pw0b, unsigned short* __restrict__ pw1b,
  unsigned short* __restrict__ pb0e, unsigned short* __restrict__ pb1e)
{
  int idx = blockIdx.x*256 + threadIdx.x;
  if (idx < 8192){ int oc=idx>>6, k=idx&63, tap=k>>5, i=k&31;
    w0e[idx] = f2bf(w0[(oc*32+i)*2+tap]); return; }
  idx -= 8192;
  if (idx < 32768){ int oc=idx>>8, k=idx&255, tap=k>>7, i=k&127;
    w1e[idx] = f2bf(w1[(oc*128+i)*2+tap]); return; }
  idx -= 32768;
  if (idx < 32768){ int oc=idx>>8, k=idx&255, tap=k>>7, i=k&127;
    w2e[idx] = f2bf(w2[(oc*128+i)*2+tap]); return; }
  idx -= 32768;
  if (idx < 262144){ pw0b[idx] = f2bf(pw0[idx]); return; }
  idx -= 262144;
  if (idx < 131072){ pw1b[idx] = f2bf(pw1[idx]); return; }
  idx -= 131072;
  if (idx < 8192){ int o=idx>>5, r=idx&31; pb0e[idx] = r<8 ? f2bf(pb0[r*256+o]) : (unsigned short)0; return; }
  idx -= 8192;
  if (idx < 2048){ int o=idx>>5, r=idx&31; pb1e[idx] = r<8 ? f2bf(pb1[r*64+o]) : (unsigned short)0; return; }
}

// ---- x (B,32,4096) fp32 -> xt (B,4111,32) bf16, 15 zero-pad rows in front ----
__global__ __launch_bounds__(64) void prep_xt(const float* __restrict__ x,
                                              unsigned short* __restrict__ xt)
{
  __shared__ float s[32][64];
  const int b = blockIdx.y, j0 = blockIdx.x*64, l = threadIdx.x;
  #pragma unroll 4
  for (int i=0;i<32;i++){
    int p = j0 + l - 15;
    s[i][l] = (p>=0 && p<4096) ? x[((size_t)b*32+i)*4096+p] : 0.f;
  }
  __syncthreads();
  const int j = j0 + l;
  if (j < NX){
    unsigned tmp[16];
    #pragma unroll
    for (int q=0;q<16;q++)
      tmp[q] = (unsigned)f2bf(s[2*q][l]) | ((unsigned)f2bf(s[2*q+1][l])<<16);
    ui4* dst = (ui4*)(xt + ((size_t)b*NX + j)*32);
    #pragma unroll
    for (int q=0;q<4;q++){ ui4 v={tmp[4*q],tmp[4*q+1],tmp[4*q+2],tmp[4*q+3]}; dst[q]=v; }
  }
}

// ---- dilated k=2 conv v4: full o128 per block, t64; act tile in LDS once;
// weights streamed wave-private global->reg (L2-resident), ZERO staging
// barriers; output restaged -> full 256B-row writes. Grid (65,8) = 520 blocks.
// 4 waves = 4 o32; wave = o32(m2) x t64(n4).
template<int IC, int DIL, int NIN, int NOUT>
__global__ __launch_bounds__(256) void conv_g(
    const unsigned short* __restrict__ act,   // [8][NIN][IC]
    const unsigned short* __restrict__ wgt,   // [128][2*IC]
    const float* __restrict__ bias,           // [128]
    unsigned short* __restrict__ outp)        // [8][NOUT][128]
{
  constexpr int KT   = 2*IC;            // 64 or 256
  constexpr int NK   = KT/32;           // 2 or 8
  constexpr int ICB  = IC*2;            // act row bytes (64 or 256)
  constexpr int ACPR = ICB/16;
  constexpr int AR   = 64 + DIL;
  constexpr int ASW  = (ICB>=256) ? 7 : 3;
  __shared__ __align__(16) char acts[AR*ICB];   // <= 17.4KB
  __shared__ __align__(16) char outs[64*256];   // [t64][o128] bf16, swizzled

  const int tid = threadIdx.x;
  const int b = blockIdx.y, tb = blockIdx.x*64;

  // stage act tile rows [tb, tb+AR), clamped
  {
    const char* ab = (const char*)(act + (size_t)b*NIN*IC);
    for (int c = tid; c < AR*ACPR; c += 256){
      int row = c / ACPR, cc = c % ACPR;
      int tg = tb + row; if (tg > NIN-1) tg = NIN-1;
      ui4 v = *(const ui4*)(ab + (size_t)tg*ICB + cc*16);
      *(ui4*)(acts + row*ICB + ((cc*16) ^ ((row&ASW)<<4))) = v;
    }
  }
  __syncthreads();

  const int wid = tid>>6, l = tid&63, lo = l&15, hi = l>>4;
  const int ow = wid*32;                       // wave's o32 of 128

  f32x4 acc[2][4];
  #pragma unroll
  for (int m=0;m<2;m++)
    #pragma unroll
    for (int n=0;n<4;n++) acc[m][n] = (f32x4){0.f,0.f,0.f,0.f};

  const unsigned short* abase = wgt + (size_t)(ow + lo)*KT + hi*8;
  #pragma unroll
  for (int kk=0;kk<NK;kk++){
    bf16x8 A0 = *(const bf16x8*)(abase + kk*32);
    bf16x8 A1 = *(const bf16x8*)(abase + 16*KT + kk*32);
    const int k = kk*32 + hi*8;
    const int tap = (k >= IC) ? 1 : 0;
    const int off2 = (k - tap*IC)*2;
    #pragma unroll
    for (int n=0;n<4;n++){
      int arow = n*16 + lo + tap*DIL;
      bf16x8 bf = *(const bf16x8*)(acts + arow*ICB + (off2 ^ ((arow&ASW)<<4)));
      acc[0][n] = __builtin_amdgcn_mfma_f32_16x16x32_bf16(A0, bf, acc[0][n], 0,0,0);
      acc[1][n] = __builtin_amdgcn_mfma_f32_16x16x32_bf16(A1, bf, acc[1][n], 0,0,0);
    }
  }

  // bias + rrelu, restage [t64][o128] swizzled
  #pragma unroll
  for (int m=0;m<2;m++){
    const int ol = ow + m*16 + hi*4;
    float b0v = bias[ol+0], b1v = bias[ol+1], b2v = bias[ol+2], b3v = bias[ol+3];
    #pragma unroll
    for (int n=0;n<4;n++){
      int tl = n*16 + lo;
      us4 v;
      v.x = f2bf(rrelu(acc[m][n][0] + b0v));
      v.y = f2bf(rrelu(acc[m][n][1] + b1v));
      v.z = f2bf(rrelu(acc[m][n][2] + b2v));
      v.w = f2bf(rrelu(acc[m][n][3] + b3v));
      *(us4*)(outs + tl*256 + ((ol*2) ^ ((tl&7)<<4))) = v;
    }
  }
  __syncthreads();
  // full 256B-row writes
  #pragma unroll
  for (int i=0;i<4;i++){
    int c = tid + i*256;
    int row = c>>4, cc = c&15;
    if (tb + row < NOUT){
      ui4 v = *(const ui4*)(outs + row*256 + ((cc*16) ^ ((row&7)<<4)));
      *(ui4*)(outp + ((size_t)b*NOUT + tb + row)*128 + cc*8) = v;
    }
  }
}

// ---- conv3(128->8,d=8) + rrelu + log-softmax + gumbel-softmax (fp32 math) ----
__global__ __launch_bounds__(64) void gumbel_g(
  const unsigned short* __restrict__ h2t,  // [8][N2][128] bf16
  const float* __restrict__ w3, const float* __restrict__ b3,
  const float* __restrict__ u,
  float* __restrict__ genz,                // [8][8][4096] fp32 (output 2)
  unsigned short* __restrict__ zt)         // [8][4096][32] bf16 (z padded to K=32)
{
  __shared__ unsigned hs[72][66];
  const int b = blockIdx.y, t0 = blockIdx.x*64, l = threadIdx.x;
  const unsigned* src = (const unsigned*)(h2t + ((size_t)b*N2 + t0)*128);
  for (int e=l; e<72*64; e+=64) hs[e>>6][e&63] = src[e];
  __syncthreads();

  float acc[8];
  #pragma unroll
  for (int r=0;r<8;r++) acc[r]=b3[r];
  for (int i2=0;i2<64;i2++){
    unsigned a0 = hs[l][i2], a1 = hs[l+8][i2];
    float v00 = bf2f(a0&0xffff), v01 = bf2f(a0>>16);
    float v10 = bf2f(a1&0xffff), v11 = bf2f(a1>>16);
    const int i = 2*i2;
    #pragma unroll
    for (int r=0;r<8;r++){
      acc[r] = fmaf(w3[(r*128+i)*2],     v00, acc[r]);
      acc[r] = fmaf(w3[(r*128+i)*2+1],   v10, acc[r]);
      acc[r] = fmaf(w3[(r*128+i+1)*2],   v01, acc[r]);
      acc[r] = fmaf(w3[(r*128+i+1)*2+1], v11, acc[r]);
    }
  }
  float m = -1e30f;
  #pragma unroll
  for (int r=0;r<8;r++){ acc[r] = rrelu(acc[r]); m = fmaxf(m, acc[r]); }
  float s = 0.f;
  #pragma unroll
  for (int r=0;r<8;r++) s += __expf(acc[r]-m);
  const float lse = m + __logf(s);
  const int t = t0 + l;
  const float* ub = u + ((size_t)b*4096 + t)*8;
  float y[8], m2 = -1e30f;
  #pragma unroll
  for (int r=0;r<8;r++){
    float g = -__logf(-__logf(ub[r]));
    y[r] = (acc[r] - lse + g)*10.f;
    m2 = fmaxf(m2, y[r]);
  }
  float s2 = 0.f;
  #pragma unroll
  for (int r=0;r<8;r++){ y[r] = __expf(y[r]-m2); s2 += y[r]; }
  const float inv = 1.f/s2;
  #pragma unroll
  for (int r=0;r<8;r++){
    y[r] *= inv;
    genz[((size_t)b*8+r)*4096 + t] = y[r];
  }
  ui4 zp = { (unsigned)f2bf(y[0]) | ((unsigned)f2bf(y[1])<<16),
             (unsigned)f2bf(y[2]) | ((unsigned)f2bf(y[3])<<16),
             (unsigned)f2bf(y[4]) | ((unsigned)f2bf(y[5])<<16),
             (unsigned)f2bf(y[6]) | ((unsigned)f2bf(y[7])<<16) };
  ui4 zz = {0,0,0,0};
  ui4* zd = (ui4*)(zt + ((size_t)b*4096 + t)*32);
  zd[0]=zp; zd[1]=zz; zd[2]=zz; zd[3]=zz;
}

// ---- MoE layer 0 v14: o64 x t128 block (1024 blocks). 4 waves = 4 o16;
// wave = o16(m1) x t128(n8). B from LDS pre-tile in-loop; A wave-private
// streamed global->reg with 1-r prefetch; zero r-loop barriers.
// hidt blocked [8][4][4096][64]: per-block contiguous 16KB write.
__global__ __launch_bounds__(256) void moe1_m(
  const unsigned short* __restrict__ h2t,  // [8][N2][128]
  const float* __restrict__ genz,
  const unsigned short* __restrict__ zt,   // [8][4096][32]
  const unsigned short* __restrict__ pw0b, // [8][256][128]
  const unsigned short* __restrict__ pb0e, // [256][32]
  unsigned short* __restrict__ hidt)       // [8][4][4096][64]
{
  __shared__ __align__(16) char pres[32768];   // [t128][256B] swizzled
  __shared__ __align__(16) char outb[16384];   // [t128][o64 -> 128B] swizzled
  __shared__ float zl[1024];                   // [8][128]

  const int ob = blockIdx.x, b = blockIdx.z, tb = blockIdx.y*128;
  const int o0g = ob*64;
  const int tid = threadIdx.x;
  #pragma unroll
  for (int i=0;i<4;i++){
    int e = tid + i*256;
    zl[e] = genz[((size_t)b*8 + (e>>7))*4096 + tb + (e&127)];
  }
  {
    const char* src = (const char*)(h2t + ((size_t)b*N2 + tb + 8)*128);
    #pragma unroll
    for (int i=0;i<8;i++){
      int c = tid + i*256, row = c>>4, cc = c&15;
      ui4 v = *(const ui4*)(src + row*256 + cc*16);
      *(ui4*)(pres + row*256 + ((cc*16) ^ ((row&7)<<4))) = v;
    }
  }
  __syncthreads();

  const int wid = tid>>6, l = tid&63, lo = l&15, hi = l>>4;
  const int ow = o0g + wid*16;                 // this wave's global o16 start

  f32x4 acc[8];
  {
    bf16x8 pf = *(const bf16x8*)(pb0e + (size_t)(ow + lo)*32 + hi*8);
    #pragma unroll
    for (int n=0;n<8;n++){
      bf16x8 zf = *(const bf16x8*)(zt + ((size_t)b*4096 + tb + n*16 + lo)*32 + hi*8);
      acc[n] = __builtin_amdgcn_mfma_f32_16x16x32_bf16(pf, zf, (f32x4){0.f,0.f,0.f,0.f}, 0,0,0);
    }
  }

  // A-frag streaming: frag(r,kk) at base + r*32768 + kk*32
  const unsigned short* abase = pw0b + (size_t)(ow + lo)*128 + hi*8;
  bf16x8 A[4], An[4];
  #pragma unroll
  for (int kk=0;kk<4;kk++) A[kk] = *(const bf16x8*)(abase + kk*32);

  #pragma unroll
  for (int r=0;r<8;r++){
    if (r < 7){
      #pragma unroll
      for (int kk=0;kk<4;kk++)
        An[kk] = *(const bf16x8*)(abase + (size_t)(r+1)*32768 + kk*32);
    }
    f32x4 ar[8];
    #pragma unroll
    for (int n=0;n<8;n++) ar[n] = (f32x4){0.f,0.f,0.f,0.f};
    #pragma unroll
    for (int kk=0;kk<4;kk++){
      #pragma unroll
      for (int n=0;n<8;n++){
        int tl = n*16 + lo;
        bf16x8 bf = *(const bf16x8*)(pres + tl*256 + ((kk*64 + hi*16) ^ ((tl&7)<<4)));
        ar[n] = __builtin_amdgcn_mfma_f32_16x16x32_bf16(A[kk], bf, ar[n], 0,0,0);
      }
    }
    #pragma unroll
    for (int n=0;n<8;n++){
      float zv = zl[r*128 + n*16 + lo];
      #pragma unroll
      for (int c2=0;c2<4;c2++)
        acc[n][c2] = fmaf(zv, ar[n][c2], acc[n][c2]);
    }
    if (r < 7){
      #pragma unroll
      for (int kk=0;kk<4;kk++) A[kk] = An[kk];
    }
  }

  // epilogue: restage [t128][o64] swizzled, then contiguous 16KB hidt write
  #pragma unroll
  for (int n=0;n<8;n++){
    int tl = n*16 + lo;
    int ol2 = (wid*16 + hi*4)*2;
    us4 v;
    v.x=f2bf(acc[n][0]); v.y=f2bf(acc[n][1]); v.z=f2bf(acc[n][2]); v.w=f2bf(acc[n][3]);
    *(us4*)(outb + tl*128 + (ol2 ^ ((tl&7)<<4))) = v;
  }
  __syncthreads();
  #pragma unroll
  for (int i=0;i<4;i++){
    int c = tid + i*256, row = c>>3, cc = c&7;
    ui4 v = *(const ui4*)(outb + row*128 + ((cc*16) ^ ((row&7)<<4)));
    *(ui4*)(hidt + (((size_t)b*4 + ob)*4096 + tb + row)*64 + cc*8) = v;
  }
}

// ---- MoE layer 1: t128 block, 8 waves x t16, dbuf LDS weight panels.
// Linear decode; hidt reads remapped for blocked layout.
__global__ __launch_bounds__(512) void moe2_m(
  const unsigned short* __restrict__ hidt, // [8][4][4096][64]
  const float* __restrict__ genz,
  const unsigned short* __restrict__ zt,
  const unsigned short* __restrict__ pw1b, // [8][64][256]
  const unsigned short* __restrict__ pb1e, // [64][32]
  float* __restrict__ out)
{
  __shared__ __align__(16) char smem[32768*2 + 4096];
  char* abuf0 = smem;
  char* abuf1 = smem + 32768;
  float* zl  = (float*)(smem + 65536);     // [8][128]

  const int wg = blockIdx.x;
  const int b = wg >> 5, tb = (wg & 31) * 128;

  const int tid = threadIdx.x;
  #pragma unroll
  for (int i=0;i<2;i++){
    int e = tid + i*512;
    zl[e] = genz[((size_t)b*8 + (e>>7))*4096 + tb + (e&127)];
  }

  const int wid = tid>>6, l = tid&63, lo = l&15, hi = l>>4;
  const int tg = tb + wid*16 + lo;

  bf16x8 bfr[8];
  #pragma unroll
  for (int kk=0;kk<8;kk++)
    bfr[kk] = *(const bf16x8*)(hidt + (((size_t)b*4 + (kk>>1))*4096 + tg)*64 + (kk&1)*32 + hi*8);
  f32x4 acc[4];
  {
    bf16x8 zf = *(const bf16x8*)(zt + ((size_t)b*4096 + tg)*32 + hi*8);
    #pragma unroll
    for (int m=0;m<4;m++){
      bf16x8 pf = *(const bf16x8*)(pb1e + (size_t)(m*16 + lo)*32 + hi*8);
      acc[m] = __builtin_amdgcn_mfma_f32_16x16x32_bf16(pf, zf, (f32x4){0.f,0.f,0.f,0.f}, 0,0,0);
    }
  }

  {
    const char* src = (const char*)pw1b;
    #pragma unroll
    for (int i=0;i<4;i++){
      int c = tid + i*512, row = c>>5, cc = c&31;
      ui4 v = *(const ui4*)(src + row*512 + cc*16);
      *(ui4*)(abuf0 + row*512 + ((cc*16) ^ ((row&7)<<4))) = v;
    }
  }
  __syncthreads();

  #pragma unroll
  for (int r=0;r<8;r++){
    char* cur = (r&1) ? abuf1 : abuf0;
    char* nxt = (r&1) ? abuf0 : abuf1;
    ui4 stg[4];
    if (r < 7){
      const char* src = (const char*)(pw1b + (size_t)(r+1)*16384);
      #pragma unroll
      for (int i=0;i<4;i++){
        int c = tid + i*512;
        stg[i] = *(const ui4*)(src + (c>>5)*512 + (c&31)*16);
      }
    }
    f32x4 ar[4];
    #pragma unroll
    for (int m=0;m<4;m++) ar[m] = (f32x4){0.f,0.f,0.f,0.f};
    #pragma unroll
    for (int kk=0;kk<8;kk++){
      #pragma unroll
      for (int m=0;m<4;m++){
        int row = m*16 + lo;
        int kb  = kk*64 + hi*16;
        bf16x8 af = *(const bf16x8*)(cur + row*512 + (kb ^ ((row&7)<<4)));
        ar[m] = __builtin_amdgcn_mfma_f32_16x16x32_bf16(af, bfr[kk], ar[m], 0,0,0);
      }
    }
    float zv = zl[r*128 + wid*16 + lo];
    #pragma unroll
    for (int m=0;m<4;m++)
      #pragma unroll
      for (int c2=0;c2<4;c2++)
        acc[m][c2] = fmaf(zv, ar[m][c2], acc[m][c2]);
    if (r < 7){
      #pragma unroll
      for (int i=0;i<4;i++){
        int c = tid + i*512;
        *(ui4*)(nxt + (c>>5)*512 + (((c&31)*16) ^ (((c>>5)&7)<<4))) = stg[i];
      }
    }
    __syncthreads();
  }

  #pragma unroll
  for (int m=0;m<4;m++){
    #pragma unroll
    for (int c2=0;c2<4;c2++){
      int o = m*16 + hi*4 + c2;
      float v = acc[m][c2];
      if (o < 32)
        out[((size_t)b*32 + o)*4096 + tg] = v;
      else {
        float e = __expf(2.f*v);
        float th = 1.f - 2.f/(e+1.f);
        out[(size_t)1048576 + ((size_t)b*32 + (o-32))*4096 + tg] = 0.5f + 0.5f*th + 0.001f;
      }
    }
  }
}

extern "C" void kernel_launch(void* const* d_in, const int* in_sizes, int n_in,
                              void* d_out, int out_size, void* d_ws, size_t ws_size,
                              hipStream_t stream) {
  const float* x   = (const float*)d_in[0];
  const float* u   = (const float*)d_in[1];
  const float* w0  = (const float*)d_in[2];
  const float* b0  = (const float*)d_in[3];
  const float* w1  = (const float*)d_in[4];
  const float* b1  = (const float*)d_in[5];
  const float* w2  = (const float*)d_in[6];
  const float* b2  = (const float*)d_in[7];
  const float* w3  = (const float*)d_in[8];
  const float* b3  = (const float*)d_in[9];
  const float* pw0 = (const float*)d_in[10];
  const float* pb0 = (const float*)d_in[11];
  const float* pw1 = (const float*)d_in[12];
  const float* pb1 = (const float*)d_in[13];

  float* out  = (float*)d_out;
  float* genz = out + (size_t)2*8*32*4096;

  char* p = (char*)d_ws;
  unsigned short* xt   = (unsigned short*)p; p += 2104832;   // 8*4111*32
  unsigned short* h0t  = (unsigned short*)p; p += 8417280;   // 8*4110*128
  unsigned short* h1t  = (unsigned short*)p; p += 8413184;   // 8*4108*128
  unsigned short* h2t  = (unsigned short*)p; p += 8404992;   // 8*4104*128
  unsigned short* ztb  = (unsigned short*)p; p += 2097152;   // 8*4096*32
  unsigned short* hidt = (unsigned short*)p; p += 16777216;  // 8*4*4096*64 (blocked)
  unsigned short* w0e  = (unsigned short*)p; p += 16384;
  unsigned short* w1e  = (unsigned short*)p; p += 65536;
  unsigned short* w2e  = (unsigned short*)p; p += 65536;
  unsigned short* pw0b = (unsigned short*)p; p += 524288;
  unsigned short* pw1b = (unsigned short*)p; p += 262144;
  unsigned short* pb0e = (unsigned short*)p; p += 16384;
  unsigned short* pb1e = (unsigned short*)p; p += 4096;

  prep_w<<<1864, 256, 0, stream>>>(w0,w1,w2,pw0,pw1,pb0,pb1,
                                   w0e,w1e,w2e,pw0b,pw1b,pb0e,pb1e);
  prep_xt<<<dim3(65,8), 64, 0, stream>>>(x, xt);
  conv_g<32,1,NX,N0><<<dim3(65,8), 256, 0, stream>>>(xt,  w0e, b0, h0t);
  conv_g<128,2,N0,N1><<<dim3(65,8), 256, 0, stream>>>(h0t, w1e, b1, h1t);
  conv_g<128,4,N1,N2><<<dim3(65,8), 256, 0, stream>>>(h1t, w2e, b2, h2t);
  gumbel_g<<<dim3(64,8), 64, 0, stream>>>(h2t, w3, b3, u, genz, ztb);
  moe1_m<<<dim3(4,32,8), 256, 0, stream>>>(h2t, genz, ztb, pw0b, pb0e, hidt);
  moe2_m<<<256, 512, 0, stream>>>(hidt, genz, ztb, pw1b, pb1e, out);
}